// Round 1
// baseline (274.125 us; speedup 1.0000x reference)
//
#include <hip/hip_runtime.h>
#include <math.h>

#define B_ 8
#define CIN_ 512
#define K_ 64
#define V_ 256
#define T_ 1024
#define KS_ 23
#define EPS_ 1e-5f

// ---------------------------------------------------------------------------
// Projection GEMM: out[b,m,t] = bias[m] + sum_c W[m,c] * in[b,c,t]
// blockIdx.y: 0 -> Wq/x -> q_raw ; 1 -> Wk/ctx -> k_buf ; 2..5 -> Wv/ctx -> v_raw
// 64x64 output tile, BK=16, 256 threads, 4x4 microtile per thread. fp32.
// ---------------------------------------------------------------------------
__global__ __launch_bounds__(256) void proj_kernel(
    const float* __restrict__ x, const float* __restrict__ ctx,
    const float* __restrict__ Wq, const float* __restrict__ bq,
    const float* __restrict__ Wk, const float* __restrict__ bk,
    const float* __restrict__ Wv, const float* __restrict__ bv,
    float* __restrict__ q_raw, float* __restrict__ k_buf, float* __restrict__ v_raw)
{
    __shared__ __align__(16) float Ws[16][64];   // [c][m]
    __shared__ __align__(16) float Xs[16][64];   // [c][t]
    const int tid = threadIdx.x;
    const int b  = blockIdx.z;
    const int t0 = blockIdx.x * 64;
    const int yb = blockIdx.y;

    const float* in; const float* W; const float* bias; float* outp;
    if (yb == 0)      { in = x;   W = Wq; bias = bq; outp = q_raw + (size_t)b * K_ * T_; }
    else if (yb == 1) { in = ctx; W = Wk; bias = bk; outp = k_buf + (size_t)b * K_ * T_; }
    else { int m0 = (yb - 2) * 64; in = ctx; W = Wv + (size_t)m0 * CIN_; bias = bv + m0;
           outp = v_raw + ((size_t)b * V_ + m0) * T_; }

    const int lm = tid >> 2, lc = (tid & 3) * 4;   // W-tile load: row, col4
    const int xc = tid >> 4, xt = (tid & 15) * 4;  // X-tile load: row, col4
    const int tx = tid & 15, ty = tid >> 4;        // microtile coords

    float acc[4][4];
    #pragma unroll
    for (int i = 0; i < 4; i++)
        #pragma unroll
        for (int j = 0; j < 4; j++) acc[i][j] = 0.f;

    for (int c0 = 0; c0 < CIN_; c0 += 16) {
        float4 wv = *(const float4*)(W + (size_t)lm * CIN_ + c0 + lc);
        float4 xv = *(const float4*)(in + ((size_t)b * CIN_ + c0 + xc) * T_ + t0 + xt);
        Ws[lc + 0][lm] = wv.x; Ws[lc + 1][lm] = wv.y; Ws[lc + 2][lm] = wv.z; Ws[lc + 3][lm] = wv.w;
        *(float4*)&Xs[xc][xt] = xv;
        __syncthreads();
        #pragma unroll
        for (int kk = 0; kk < 16; kk++) {
            float a0 = Ws[kk][ty * 4 + 0], a1 = Ws[kk][ty * 4 + 1];
            float a2 = Ws[kk][ty * 4 + 2], a3 = Ws[kk][ty * 4 + 3];
            float b0 = Xs[kk][tx * 4 + 0], b1 = Xs[kk][tx * 4 + 1];
            float b2 = Xs[kk][tx * 4 + 2], b3 = Xs[kk][tx * 4 + 3];
            acc[0][0] += a0 * b0; acc[0][1] += a0 * b1; acc[0][2] += a0 * b2; acc[0][3] += a0 * b3;
            acc[1][0] += a1 * b0; acc[1][1] += a1 * b1; acc[1][2] += a1 * b2; acc[1][3] += a1 * b3;
            acc[2][0] += a2 * b0; acc[2][1] += a2 * b1; acc[2][2] += a2 * b2; acc[2][3] += a2 * b3;
            acc[3][0] += a3 * b0; acc[3][1] += a3 * b1; acc[3][2] += a3 * b2; acc[3][3] += a3 * b3;
        }
        __syncthreads();
    }
    #pragma unroll
    for (int i = 0; i < 4; i++) {
        float bi = bias[ty * 4 + i];
        float4 o = make_float4(acc[i][0] + bi, acc[i][1] + bi, acc[i][2] + bi, acc[i][3] + bi);
        *(float4*)(outp + (size_t)(ty * 4 + i) * T_ + t0 + tx * 4) = o;
    }
}

// ---------------------------------------------------------------------------
// BatchNorm stats: per channel, mean/var over (b,t); emit scale/shift.
// blocks 0..63 -> Q channels, 64..319 -> V channels.
// ---------------------------------------------------------------------------
__global__ __launch_bounds__(256) void bnstats_kernel(
    const float* __restrict__ q_raw, const float* __restrict__ v_raw,
    const float* __restrict__ gq, const float* __restrict__ betaq,
    const float* __restrict__ gv, const float* __restrict__ betav,
    float* __restrict__ qprm, float* __restrict__ vprm)
{
    __shared__ float rs[256], rq[256];
    const int tid = threadIdx.x, ch = blockIdx.x;
    const float* src; int C, c; float gamma, beta; float *scl, *shf;
    if (ch < K_) { c = ch;      src = q_raw; C = K_; gamma = gq[c]; beta = betaq[c]; scl = qprm + c; shf = qprm + K_ + c; }
    else         { c = ch - K_; src = v_raw; C = V_; gamma = gv[c]; beta = betav[c]; scl = vprm + c; shf = vprm + V_ + c; }
    float s = 0.f, sq = 0.f;
    for (int i = tid; i < B_ * T_; i += 256) {
        int b = i >> 10, t = i & (T_ - 1);
        float v = src[((size_t)b * C + c) * T_ + t];
        s += v; sq += v * v;
    }
    rs[tid] = s; rq[tid] = sq; __syncthreads();
    for (int st = 128; st > 0; st >>= 1) {
        if (tid < st) { rs[tid] += rs[tid + st]; rq[tid] += rq[tid + st]; }
        __syncthreads();
    }
    if (tid == 0) {
        float mean = rs[0] * (1.f / (B_ * T_));
        float var  = rq[0] * (1.f / (B_ * T_)) - mean * mean;
        float sc = gamma * rsqrtf(var + EPS_);
        *scl = sc; *shf = beta - mean * sc;
    }
}

// ---------------------------------------------------------------------------
// In-place softmax over T for each (b,k) row of k_buf.
// ---------------------------------------------------------------------------
__global__ __launch_bounds__(256) void softmax_kernel(float* __restrict__ k_buf)
{
    __shared__ float red[256];
    const int tid = threadIdx.x;
    float4* row = (float4*)(k_buf + (size_t)blockIdx.x * T_);
    float4 v = row[tid];
    float mx = fmaxf(fmaxf(v.x, v.y), fmaxf(v.z, v.w));
    red[tid] = mx; __syncthreads();
    for (int st = 128; st > 0; st >>= 1) {
        if (tid < st) red[tid] = fmaxf(red[tid], red[tid + st]);
        __syncthreads();
    }
    mx = red[0]; __syncthreads();
    float4 e;
    e.x = __expf(v.x - mx); e.y = __expf(v.y - mx);
    e.z = __expf(v.z - mx); e.w = __expf(v.w - mx);
    red[tid] = e.x + e.y + e.z + e.w; __syncthreads();
    for (int st = 128; st > 0; st >>= 1) {
        if (tid < st) red[tid] += red[tid + st];
        __syncthreads();
    }
    float inv = 1.f / red[0];
    e.x *= inv; e.y *= inv; e.z *= inv; e.w *= inv;
    row[tid] = e;
}

// ---------------------------------------------------------------------------
// content_lambda[b,k,v] = sum_t nk[b,k,t] * (v_raw[b,v,t]*vs[v] + vh[v])
// One block per (b,k); nk row staged in LDS; thread v accumulates over t.
// ---------------------------------------------------------------------------
__global__ __launch_bounds__(256) void lambda_kernel(
    const float* __restrict__ k_buf, const float* __restrict__ v_raw,
    const float* __restrict__ vprm, float* __restrict__ cl)
{
    __shared__ __align__(16) float nk[T_];
    const int tid = threadIdx.x;
    const int bk = blockIdx.x;      // b*K_ + k
    const int b = bk >> 6;
    ((float4*)nk)[tid] = ((const float4*)(k_buf + (size_t)bk * T_))[tid];
    __syncthreads();
    const int v = tid;
    const float4* vr = (const float4*)(v_raw + ((size_t)b * V_ + v) * T_);
    const float vs = vprm[v], vh = vprm[V_ + v];
    float a0 = 0, a1 = 0, a2 = 0, a3 = 0;
    for (int i = 0; i < T_ / 4; i++) {
        float4 xv = vr[i]; float4 n = ((float4*)nk)[i];
        a0 += n.x * (xv.x * vs + vh); a1 += n.y * (xv.y * vs + vh);
        a2 += n.z * (xv.z * vs + vh); a3 += n.w * (xv.w * vs + vh);
    }
    cl[(size_t)bk * V_ + v] = a0 + a1 + a2 + a3;
}

// ---------------------------------------------------------------------------
// qp[b,s,t] = sum_k q_bn[b,k,t] * pos_w[k,s]  (s<KS_) ; qp[b,KS_,t] = q.pos_b
// ---------------------------------------------------------------------------
__global__ __launch_bounds__(256) void qp_kernel(
    const float* __restrict__ q_raw, const float* __restrict__ pos_w,
    const float* __restrict__ pos_b, const float* __restrict__ qprm,
    float* __restrict__ qp)
{
    __shared__ float pw[K_ * KS_];
    __shared__ float pbs[K_], qss[K_], qhs[K_];
    const int tid = threadIdx.x;
    for (int i = tid; i < K_ * KS_; i += 256) pw[i] = pos_w[i];
    if (tid < K_) { pbs[tid] = pos_b[tid]; qss[tid] = qprm[tid]; qhs[tid] = qprm[K_ + tid]; }
    __syncthreads();
    const int gid = blockIdx.x * 256 + tid;
    const int b = gid >> 10, t = gid & (T_ - 1);
    float accum[KS_ + 1];
    #pragma unroll
    for (int s = 0; s < KS_ + 1; s++) accum[s] = 0.f;
    for (int k = 0; k < K_; k++) {
        float q = q_raw[((size_t)b * K_ + k) * T_ + t] * qss[k] + qhs[k];
        #pragma unroll
        for (int s = 0; s < KS_; s++) accum[s] += q * pw[k * KS_ + s];
        accum[KS_] += q * pbs[k];
    }
    #pragma unroll
    for (int s = 0; s < KS_ + 1; s++)
        qp[((size_t)b * (KS_ + 1) + s) * T_ + t] = accum[s];
}

// ---------------------------------------------------------------------------
// out[b,v,t] = qb[b,t] + sum_k q_bn[b,k,t]*cl[b,k,v]
//            + sum_s qp[b,s,t] * v_bn[b,v,t+s-11]   (zero-padded)
// ---------------------------------------------------------------------------
__global__ __launch_bounds__(256) void out_kernel(
    const float* __restrict__ q_raw, const float* __restrict__ v_raw,
    const float* __restrict__ cl, const float* __restrict__ qp,
    const float* __restrict__ qprm, const float* __restrict__ vprm,
    float* __restrict__ out)
{
    __shared__ float clv[K_], qss[K_], qhs[K_];
    const int tid = threadIdx.x;
    const int b = blockIdx.z, v = blockIdx.y;
    const int t = blockIdx.x * 256 + tid;
    if (tid < K_) {
        clv[tid] = cl[((size_t)b * K_ + tid) * V_ + v];
        qss[tid] = qprm[tid]; qhs[tid] = qprm[K_ + tid];
    }
    __syncthreads();
    float acc = qp[((size_t)b * (KS_ + 1) + KS_) * T_ + t];   // pos_b dot term
    const float* qrow = q_raw + (size_t)b * K_ * T_ + t;
    #pragma unroll 8
    for (int k = 0; k < K_; k++)
        acc += (qrow[(size_t)k * T_] * qss[k] + qhs[k]) * clv[k];
    const float vs = vprm[v], vh = vprm[V_ + v];
    const float* vrow = v_raw + ((size_t)b * V_ + v) * T_;
    const float* qpb  = qp + (size_t)b * (KS_ + 1) * T_ + t;
    #pragma unroll
    for (int s = 0; s < KS_; s++) {
        int tt = t + s - KS_ / 2;
        if (tt >= 0 && tt < T_)
            acc += qpb[(size_t)s * T_] * (vrow[tt] * vs + vh);
    }
    out[((size_t)b * V_ + v) * T_ + t] = acc;
}

extern "C" void kernel_launch(void* const* d_in, const int* in_sizes, int n_in,
                              void* d_out, int out_size, void* d_ws, size_t ws_size,
                              hipStream_t stream)
{
    const float* x     = (const float*)d_in[0];
    const float* ctx   = (const float*)d_in[1];
    const float* Wq    = (const float*)d_in[2];
    const float* bq    = (const float*)d_in[3];
    const float* Wk    = (const float*)d_in[4];
    const float* bk    = (const float*)d_in[5];
    const float* Wv    = (const float*)d_in[6];
    const float* bv    = (const float*)d_in[7];
    const float* gq    = (const float*)d_in[8];
    const float* betaq = (const float*)d_in[9];
    const float* gv    = (const float*)d_in[10];
    const float* betav = (const float*)d_in[11];
    const float* pos_w = (const float*)d_in[12];
    const float* pos_b = (const float*)d_in[13];
    float* out = (float*)d_out;

    float* ws    = (float*)d_ws;
    float* q_raw = ws;                                  // B*K*T   = 524288
    float* k_buf = q_raw + (size_t)B_ * K_ * T_;        // B*K*T   = 524288
    float* v_raw = k_buf + (size_t)B_ * K_ * T_;        // B*V*T   = 2097152
    float* cl    = v_raw + (size_t)B_ * V_ * T_;        // B*K*V   = 131072
    float* qp    = cl + (size_t)B_ * K_ * V_;           // B*24*T  = 196608
    float* qprm  = qp + (size_t)B_ * (KS_ + 1) * T_;    // 128
    float* vprm  = qprm + 2 * K_;                       // 512

    proj_kernel<<<dim3(T_ / 64, 6, B_), 256, 0, stream>>>(
        x, ctx, Wq, bq, Wk, bk, Wv, bv, q_raw, k_buf, v_raw);
    bnstats_kernel<<<dim3(K_ + V_), 256, 0, stream>>>(
        q_raw, v_raw, gq, betaq, gv, betav, qprm, vprm);
    softmax_kernel<<<dim3(B_ * K_), 256, 0, stream>>>(k_buf);
    lambda_kernel<<<dim3(B_ * K_), 256, 0, stream>>>(k_buf, v_raw, vprm, cl);
    qp_kernel<<<dim3(B_ * T_ / 256), 256, 0, stream>>>(
        q_raw, pos_w, pos_b, qprm, qp);
    out_kernel<<<dim3(T_ / 256, V_, B_), 256, 0, stream>>>(
        q_raw, v_raw, cl, qp, qprm, vprm, out);
}

// Round 3
// 215.633 us; speedup vs baseline: 1.2713x; 1.2713x over previous
//
#include <hip/hip_runtime.h>
#include <math.h>

#define B_ 8
#define CIN_ 512
#define K_ 64
#define V_ 256
#define T_ 1024
#define KS_ 23
#define EPS_ 1e-5f

// ---------------------------------------------------------------------------
// Projection GEMM: out[b,m,t] = bias[m] + sum_c W[m,c] * in[b,c,t]
// (unchanged — bf16 MFMA planned next round)
// ---------------------------------------------------------------------------
__global__ __launch_bounds__(256) void proj_kernel(
    const float* __restrict__ x, const float* __restrict__ ctx,
    const float* __restrict__ Wq, const float* __restrict__ bq,
    const float* __restrict__ Wk, const float* __restrict__ bk,
    const float* __restrict__ Wv, const float* __restrict__ bv,
    float* __restrict__ q_raw, float* __restrict__ k_buf, float* __restrict__ v_raw)
{
    __shared__ __align__(16) float Ws[16][64];   // [c][m]
    __shared__ __align__(16) float Xs[16][64];   // [c][t]
    const int tid = threadIdx.x;
    const int b  = blockIdx.z;
    const int t0 = blockIdx.x * 64;
    const int yb = blockIdx.y;

    const float* in; const float* W; const float* bias; float* outp;
    if (yb == 0)      { in = x;   W = Wq; bias = bq; outp = q_raw + (size_t)b * K_ * T_; }
    else if (yb == 1) { in = ctx; W = Wk; bias = bk; outp = k_buf + (size_t)b * K_ * T_; }
    else { int m0 = (yb - 2) * 64; in = ctx; W = Wv + (size_t)m0 * CIN_; bias = bv + m0;
           outp = v_raw + ((size_t)b * V_ + m0) * T_; }

    const int lm = tid >> 2, lc = (tid & 3) * 4;
    const int xc = tid >> 4, xt = (tid & 15) * 4;
    const int tx = tid & 15, ty = tid >> 4;

    float acc[4][4];
    #pragma unroll
    for (int i = 0; i < 4; i++)
        #pragma unroll
        for (int j = 0; j < 4; j++) acc[i][j] = 0.f;

    for (int c0 = 0; c0 < CIN_; c0 += 16) {
        float4 wv = *(const float4*)(W + (size_t)lm * CIN_ + c0 + lc);
        float4 xv = *(const float4*)(in + ((size_t)b * CIN_ + c0 + xc) * T_ + t0 + xt);
        Ws[lc + 0][lm] = wv.x; Ws[lc + 1][lm] = wv.y; Ws[lc + 2][lm] = wv.z; Ws[lc + 3][lm] = wv.w;
        *(float4*)&Xs[xc][xt] = xv;
        __syncthreads();
        #pragma unroll
        for (int kk = 0; kk < 16; kk++) {
            float a0 = Ws[kk][ty * 4 + 0], a1 = Ws[kk][ty * 4 + 1];
            float a2 = Ws[kk][ty * 4 + 2], a3 = Ws[kk][ty * 4 + 3];
            float b0 = Xs[kk][tx * 4 + 0], b1 = Xs[kk][tx * 4 + 1];
            float b2 = Xs[kk][tx * 4 + 2], b3 = Xs[kk][tx * 4 + 3];
            acc[0][0] += a0 * b0; acc[0][1] += a0 * b1; acc[0][2] += a0 * b2; acc[0][3] += a0 * b3;
            acc[1][0] += a1 * b0; acc[1][1] += a1 * b1; acc[1][2] += a1 * b2; acc[1][3] += a1 * b3;
            acc[2][0] += a2 * b0; acc[2][1] += a2 * b1; acc[2][2] += a2 * b2; acc[2][3] += a2 * b3;
            acc[3][0] += a3 * b0; acc[3][1] += a3 * b1; acc[3][2] += a3 * b2; acc[3][3] += a3 * b3;
        }
        __syncthreads();
    }
    #pragma unroll
    for (int i = 0; i < 4; i++) {
        float bi = bias[ty * 4 + i];
        float4 o = make_float4(acc[i][0] + bi, acc[i][1] + bi, acc[i][2] + bi, acc[i][3] + bi);
        *(float4*)(outp + (size_t)(ty * 4 + i) * T_ + t0 + tx * 4) = o;
    }
}

// ---------------------------------------------------------------------------
// BatchNorm stats (unchanged)
// ---------------------------------------------------------------------------
__global__ __launch_bounds__(256) void bnstats_kernel(
    const float* __restrict__ q_raw, const float* __restrict__ v_raw,
    const float* __restrict__ gq, const float* __restrict__ betaq,
    const float* __restrict__ gv, const float* __restrict__ betav,
    float* __restrict__ qprm, float* __restrict__ vprm)
{
    __shared__ float rs[256], rq[256];
    const int tid = threadIdx.x, ch = blockIdx.x;
    const float* src; int C, c; float gamma, beta; float *scl, *shf;
    if (ch < K_) { c = ch;      src = q_raw; C = K_; gamma = gq[c]; beta = betaq[c]; scl = qprm + c; shf = qprm + K_ + c; }
    else         { c = ch - K_; src = v_raw; C = V_; gamma = gv[c]; beta = betav[c]; scl = vprm + c; shf = vprm + V_ + c; }
    float s = 0.f, sq = 0.f;
    for (int i = tid; i < B_ * T_; i += 256) {
        int b = i >> 10, t = i & (T_ - 1);
        float v = src[((size_t)b * C + c) * T_ + t];
        s += v; sq += v * v;
    }
    rs[tid] = s; rq[tid] = sq; __syncthreads();
    for (int st = 128; st > 0; st >>= 1) {
        if (tid < st) { rs[tid] += rs[tid + st]; rq[tid] += rq[tid + st]; }
        __syncthreads();
    }
    if (tid == 0) {
        float mean = rs[0] * (1.f / (B_ * T_));
        float var  = rq[0] * (1.f / (B_ * T_)) - mean * mean;
        float sc = gamma * rsqrtf(var + EPS_);
        *scl = sc; *shf = beta - mean * sc;
    }
}

// ---------------------------------------------------------------------------
// Softmax over T (unchanged)
// ---------------------------------------------------------------------------
__global__ __launch_bounds__(256) void softmax_kernel(float* __restrict__ k_buf)
{
    __shared__ float red[256];
    const int tid = threadIdx.x;
    float4* row = (float4*)(k_buf + (size_t)blockIdx.x * T_);
    float4 v = row[tid];
    float mx = fmaxf(fmaxf(v.x, v.y), fmaxf(v.z, v.w));
    red[tid] = mx; __syncthreads();
    for (int st = 128; st > 0; st >>= 1) {
        if (tid < st) red[tid] = fmaxf(red[tid], red[tid + st]);
        __syncthreads();
    }
    mx = red[0]; __syncthreads();
    float4 e;
    e.x = __expf(v.x - mx); e.y = __expf(v.y - mx);
    e.z = __expf(v.z - mx); e.w = __expf(v.w - mx);
    red[tid] = e.x + e.y + e.z + e.w; __syncthreads();
    for (int st = 128; st > 0; st >>= 1) {
        if (tid < st) red[tid] += red[tid + st];
        __syncthreads();
    }
    float inv = 1.f / red[0];
    e.x *= inv; e.y *= inv; e.z *= inv; e.w *= inv;
    row[tid] = e;
}

// ---------------------------------------------------------------------------
// Zero-fill for cl (replaces hipMemsetAsync — graph-capture-safe for sure).
// ---------------------------------------------------------------------------
__global__ __launch_bounds__(256) void zero_kernel(float4* __restrict__ p)
{
    p[blockIdx.x * 256 + threadIdx.x] = make_float4(0.f, 0.f, 0.f, 0.f);
}

// ---------------------------------------------------------------------------
// lambda2: cl_raw[b,k,v] += sum_t nk[b,k,t] * v_raw[b,v,t]   (t-split, atomic)
// BN on v folded at consumption (sum_t nk = 1). t-chunk 64 keeps LDS at
// 34,816 B (R2's 128-chunk was 68.6 KB > 64 KiB static limit -> crash).
// ---------------------------------------------------------------------------
__global__ __launch_bounds__(256) void lambda_kernel2(
    const float* __restrict__ k_buf, const float* __restrict__ v_raw,
    float* __restrict__ cl)
{
    __shared__ __align__(16) float nks[K_][68];   // [k][t]
    __shared__ __align__(16) float vls[64][68];   // [t][v]
    const int tid = threadIdx.x;
    const int b = blockIdx.z, v0 = blockIdx.y * 64, t0 = blockIdx.x * 64;

    {
        const int r = tid >> 2, q = tid & 3;
        const float* nrow = k_buf + ((size_t)b * K_ + r) * T_ + t0;
        const float* vrow = v_raw + ((size_t)b * V_ + v0 + r) * T_ + t0;
        #pragma unroll
        for (int i = 0; i < 4; i++) {
            int c4 = q + 4 * i;
            float4 g = *(const float4*)(nrow + 4 * c4);
            *(float4*)&nks[r][4 * c4] = g;
            float4 h = *(const float4*)(vrow + 4 * c4);
            vls[4 * c4 + 0][r] = h.x; vls[4 * c4 + 1][r] = h.y;
            vls[4 * c4 + 2][r] = h.z; vls[4 * c4 + 3][r] = h.w;
        }
    }
    __syncthreads();

    const int tv = tid & 15, tk = tid >> 4;   // k = 4*tk+i, v = v0 + 4*tv+j
    float4 acc[4];
    #pragma unroll
    for (int i = 0; i < 4; i++) acc[i] = make_float4(0.f, 0.f, 0.f, 0.f);

    for (int tt = 0; tt < 16; tt++) {
        float4 w0 = *(float4*)&vls[4 * tt + 0][4 * tv];
        float4 w1 = *(float4*)&vls[4 * tt + 1][4 * tv];
        float4 w2 = *(float4*)&vls[4 * tt + 2][4 * tv];
        float4 w3 = *(float4*)&vls[4 * tt + 3][4 * tv];
        #pragma unroll
        for (int i = 0; i < 4; i++) {
            float4 n = *(float4*)&nks[4 * tk + i][4 * tt];
            acc[i] += w0 * n.x + w1 * n.y + w2 * n.z + w3 * n.w;
        }
    }
    #pragma unroll
    for (int i = 0; i < 4; i++) {
        float* ap = (float*)&acc[i];
        #pragma unroll
        for (int j = 0; j < 4; j++)
            atomicAdd(&cl[((size_t)b * K_ + 4 * tk + i) * V_ + v0 + 4 * tv + j], ap[j]);
    }
}

// ---------------------------------------------------------------------------
// qp2 (unchanged from R2)
// ---------------------------------------------------------------------------
__global__ __launch_bounds__(256) void qp_kernel2(
    const float* __restrict__ q_raw, const float* __restrict__ pos_w,
    const float* __restrict__ pos_b, const float* __restrict__ qprm,
    float* __restrict__ qp)
{
    __shared__ float pw[K_ * KS_];
    __shared__ float pb[K_];
    __shared__ float red[4][64][KS_ + 2];
    const int tid = threadIdx.x;
    for (int i = tid; i < K_ * KS_; i += 256) pw[i] = pos_w[i];
    if (tid < K_) pb[tid] = pos_b[tid];
    __syncthreads();
    const int b = blockIdx.x >> 4, t0 = (blockIdx.x & 15) * 64;
    const int tl = tid & 63, kq = tid >> 6;
    float accum[KS_ + 1];
    #pragma unroll
    for (int s = 0; s <= KS_; s++) accum[s] = 0.f;
    for (int kk = 0; kk < 16; kk++) {
        int k = kq * 16 + kk;
        float qv = q_raw[((size_t)b * K_ + k) * T_ + t0 + tl] * qprm[k] + qprm[K_ + k];
        #pragma unroll
        for (int s = 0; s < KS_; s++) accum[s] += qv * pw[k * KS_ + s];
        accum[KS_] += qv * pb[k];
    }
    #pragma unroll
    for (int s = 0; s <= KS_; s++) red[kq][tl][s] = accum[s];
    __syncthreads();
    for (int idx = tid; idx < 64 * (KS_ + 1); idx += 256) {
        int t = idx / (KS_ + 1), s = idx % (KS_ + 1);
        float v = red[0][t][s] + red[1][t][s] + red[2][t][s] + red[3][t][s];
        qp[((size_t)b * (KS_ + 1) + s) * T_ + t0 + t] = v;
    }
}

// ---------------------------------------------------------------------------
// out2 (unchanged from R2): out[b,v,t] = qb + sum_k qbn*clb + sum_s qp*vbn
// ---------------------------------------------------------------------------
__global__ __launch_bounds__(256) void out_kernel2(
    const float* __restrict__ q_raw, const float* __restrict__ v_raw,
    const float* __restrict__ cl, const float* __restrict__ qp,
    const float* __restrict__ qprm, const float* __restrict__ vprm,
    float* __restrict__ out)
{
    __shared__ __align__(16) float qs[K_][68];        // [k][t]  BN'd q
    __shared__ __align__(16) float clb[K_][68];       // [k][v]  affine'd cl
    __shared__ __align__(16) float qps[KS_ + 1][68];  // [s][t]
    __shared__ __align__(16) float vs2[64][90];       // [v][c], c0 = t0-11
    const int tid = threadIdx.x;
    const int b = blockIdx.z, v0 = blockIdx.y * 64, t0 = blockIdx.x * 64;

    {
        const int k = tid >> 2, q = tid & 3;
        const float s = qprm[k], h = qprm[K_ + k];
        const float* qrow = q_raw + ((size_t)b * K_ + k) * T_ + t0;
        const float* crow = cl + ((size_t)b * K_ + k) * V_ + v0;
        #pragma unroll
        for (int i = 0; i < 4; i++) {
            int c4 = q + 4 * i;
            float4 g = *(const float4*)(qrow + 4 * c4);
            float4 o = make_float4(g.x * s + h, g.y * s + h, g.z * s + h, g.w * s + h);
            *(float4*)&qs[k][4 * c4] = o;
            float4 c  = *(const float4*)(crow + 4 * c4);
            float4 sv = *(const float4*)&vprm[v0 + 4 * c4];
            float4 hv = *(const float4*)&vprm[V_ + v0 + 4 * c4];
            float4 cb = make_float4(c.x * sv.x + hv.x, c.y * sv.y + hv.y,
                                    c.z * sv.z + hv.z, c.w * sv.w + hv.w);
            *(float4*)&clb[k][4 * c4] = cb;
        }
    }
    for (int idx = tid; idx < (KS_ + 1) * 16; idx += 256) {
        int s = idx >> 4, c4 = idx & 15;
        *(float4*)&qps[s][4 * c4] =
            *(const float4*)(qp + ((size_t)b * (KS_ + 1) + s) * T_ + t0 + 4 * c4);
    }
    {
        const int v = tid >> 2, q = tid & 3;
        const float sv = vprm[v0 + v], hv = vprm[V_ + v0 + v];
        const float* vrow = v_raw + ((size_t)b * V_ + v0 + v) * T_;
        #pragma unroll
        for (int i = 0; i < 22; i++) {
            int c = q + 4 * i;
            if (c < 86) {
                int t = t0 - 11 + c;
                vs2[v][c] = (t >= 0 && t < T_) ? vrow[t] * sv + hv : 0.f;
            }
        }
    }
    __syncthreads();

    const int tx = tid & 15, ty = tid >> 4;  // t = tx+16i, v = 4*ty+j
    float4 acc[4];
    #pragma unroll
    for (int i = 0; i < 4; i++) acc[i] = make_float4(0.f, 0.f, 0.f, 0.f);

    for (int k = 0; k < K_; k++) {
        float4 cv = *(float4*)&clb[k][4 * ty];
        acc[0] += cv * qs[k][tx];
        acc[1] += cv * qs[k][tx + 16];
        acc[2] += cv * qs[k][tx + 32];
        acc[3] += cv * qs[k][tx + 48];
    }
    #pragma unroll 1
    for (int s = 0; s < KS_; s++) {
        #pragma unroll
        for (int i = 0; i < 4; i++) {
            float qpl = qps[s][tx + 16 * i];
            int c = tx + 16 * i + s;
            float4 vv = make_float4(vs2[4 * ty + 0][c], vs2[4 * ty + 1][c],
                                    vs2[4 * ty + 2][c], vs2[4 * ty + 3][c]);
            acc[i] += vv * qpl;
        }
    }
    #pragma unroll
    for (int i = 0; i < 4; i++) {
        float qb = qps[KS_][tx + 16 * i];
        float* ap = (float*)&acc[i];
        #pragma unroll
        for (int j = 0; j < 4; j++)
            out[((size_t)b * V_ + v0 + 4 * ty + j) * T_ + t0 + tx + 16 * i] = ap[j] + qb;
    }
}

extern "C" void kernel_launch(void* const* d_in, const int* in_sizes, int n_in,
                              void* d_out, int out_size, void* d_ws, size_t ws_size,
                              hipStream_t stream)
{
    const float* x     = (const float*)d_in[0];
    const float* ctx   = (const float*)d_in[1];
    const float* Wq    = (const float*)d_in[2];
    const float* bq    = (const float*)d_in[3];
    const float* Wk    = (const float*)d_in[4];
    const float* bk    = (const float*)d_in[5];
    const float* Wv    = (const float*)d_in[6];
    const float* bv    = (const float*)d_in[7];
    const float* gq    = (const float*)d_in[8];
    const float* betaq = (const float*)d_in[9];
    const float* gv    = (const float*)d_in[10];
    const float* betav = (const float*)d_in[11];
    const float* pos_w = (const float*)d_in[12];
    const float* pos_b = (const float*)d_in[13];
    float* out = (float*)d_out;

    float* ws    = (float*)d_ws;
    float* q_raw = ws;                                  // B*K*T
    float* k_buf = q_raw + (size_t)B_ * K_ * T_;        // B*K*T
    float* v_raw = k_buf + (size_t)B_ * K_ * T_;        // B*V*T
    float* cl    = v_raw + (size_t)B_ * V_ * T_;        // B*K*V (raw dot)
    float* qp    = cl + (size_t)B_ * K_ * V_;           // B*24*T
    float* qprm  = qp + (size_t)B_ * (KS_ + 1) * T_;    // 2*K
    float* vprm  = qprm + 2 * K_;                       // 2*V

    proj_kernel<<<dim3(T_ / 64, 6, B_), 256, 0, stream>>>(
        x, ctx, Wq, bq, Wk, bk, Wv, bv, q_raw, k_buf, v_raw);
    bnstats_kernel<<<dim3(K_ + V_), 256, 0, stream>>>(
        q_raw, v_raw, gq, betaq, gv, betav, qprm, vprm);
    softmax_kernel<<<dim3(B_ * K_), 256, 0, stream>>>(k_buf);
    zero_kernel<<<dim3(B_ * K_ * V_ / 1024), 256, 0, stream>>>((float4*)cl);
    lambda_kernel2<<<dim3(T_ / 64, V_ / 64, B_), 256, 0, stream>>>(k_buf, v_raw, cl);
    qp_kernel2<<<dim3(B_ * T_ / 64), 256, 0, stream>>>(
        q_raw, pos_w, pos_b, qprm, qp);
    out_kernel2<<<dim3(T_ / 64, V_ / 64, B_), 256, 0, stream>>>(
        q_raw, v_raw, cl, qp, qprm, vprm, out);
}

// Round 4
// 191.905 us; speedup vs baseline: 1.4284x; 1.1236x over previous
//
#include <hip/hip_runtime.h>
#include <math.h>

#define B_ 8
#define CIN_ 512
#define K_ 64
#define V_ 256
#define T_ 1024
#define KS_ 23
#define EPS_ 1e-5f

typedef __attribute__((ext_vector_type(8))) short bf16x8;
typedef __attribute__((ext_vector_type(4))) float f32x4;

__device__ __forceinline__ unsigned short f2bf(float f) {
    union { float f; unsigned u; } x; x.f = f;
    unsigned r = x.u + 0x7fffu + ((x.u >> 16) & 1u);   // RNE
    return (unsigned short)(r >> 16);
}

// ---------------------------------------------------------------------------
// proj_mfma: out[b,m,t] = bias[m] + sum_c W[m,c]*in[b,c,t], bf16 MFMA.
// Block tile 64m x 128t, BK=64. LDS: W bf16 [64][72], X^T bf16 [128][72].
// 4 waves, each 16m x 128t = 8 accs of 16x16. mfma_f32_16x16x32_bf16.
// A: lane m=l&15, k=(l>>4)*8+j ; B: n=l&15, k=(l>>4)*8+j ; D: col=l&15,
// row=(l>>4)*4+reg  (layouts per m89/m91/m120 verified mappings).
// ---------------------------------------------------------------------------
__global__ __launch_bounds__(256) void proj_mfma(
    const float* __restrict__ x, const float* __restrict__ ctx,
    const float* __restrict__ Wq, const float* __restrict__ bq,
    const float* __restrict__ Wk, const float* __restrict__ bk,
    const float* __restrict__ Wv, const float* __restrict__ bv,
    float* __restrict__ q_raw, float* __restrict__ k_buf, float* __restrict__ v_raw)
{
    __shared__ short Wt[64][72];
    __shared__ short Xt[128][72];
    const int tid = threadIdx.x;
    const int b  = blockIdx.z;
    const int t0 = blockIdx.x * 128;
    const int yb = blockIdx.y;

    const float* in; const float* W; const float* bias; float* outp;
    if (yb == 0)      { in = x;   W = Wq; bias = bq; outp = q_raw + (size_t)b * K_ * T_; }
    else if (yb == 1) { in = ctx; W = Wk; bias = bk; outp = k_buf + (size_t)b * K_ * T_; }
    else { int m0 = (yb - 2) * 64; in = ctx; W = Wv + (size_t)m0 * CIN_; bias = bv + m0;
           outp = v_raw + ((size_t)b * V_ + m0) * T_; }

    const int lane = tid & 63, w = tid >> 6;
    const int lm = tid >> 2, lq = tid & 3;    // W staging: row, col-quarter
    const int xp = tid & 31, xg = tid >> 5;   // X staging: c-pair, t-group

    f32x4 acc[8];
    #pragma unroll
    for (int j = 0; j < 8; j++) acc[j] = (f32x4){0.f, 0.f, 0.f, 0.f};

    for (int c0 = 0; c0 < CIN_; c0 += 64) {
        // ---- stage W tile (64m x 64c) as bf16 [m][c] ----
        #pragma unroll
        for (int u = 0; u < 4; u++) {
            float4 wv = *(const float4*)(W + (size_t)lm * CIN_ + c0 + lq * 16 + 4 * u);
            ushort4 h;
            h.x = f2bf(wv.x); h.y = f2bf(wv.y); h.z = f2bf(wv.z); h.w = f2bf(wv.w);
            *(ushort4*)&Wt[lm][lq * 16 + 4 * u] = h;
        }
        // ---- stage X tile (64c x 128t) transposed -> bf16 [t][c] ----
        {
            const float* r0 = in + ((size_t)b * CIN_ + c0 + 2 * xp) * T_ + t0 + xg * 16;
            #pragma unroll
            for (int u = 0; u < 4; u++) {
                float4 a = *(const float4*)(r0 + 4 * u);
                float4 c = *(const float4*)(r0 + T_ + 4 * u);
                ushort2 p;
                p.x = f2bf(a.x); p.y = f2bf(c.x);
                *(ushort2*)&Xt[xg * 16 + 4 * u + 0][2 * xp] = p;
                p.x = f2bf(a.y); p.y = f2bf(c.y);
                *(ushort2*)&Xt[xg * 16 + 4 * u + 1][2 * xp] = p;
                p.x = f2bf(a.z); p.y = f2bf(c.z);
                *(ushort2*)&Xt[xg * 16 + 4 * u + 2][2 * xp] = p;
                p.x = f2bf(a.w); p.y = f2bf(c.w);
                *(ushort2*)&Xt[xg * 16 + 4 * u + 3][2 * xp] = p;
            }
        }
        __syncthreads();
        #pragma unroll
        for (int ks = 0; ks < 2; ks++) {
            const int kc = ks * 32 + (lane >> 4) * 8;
            bf16x8 af = *(bf16x8*)&Wt[w * 16 + (lane & 15)][kc];
            #pragma unroll
            for (int j = 0; j < 8; j++) {
                bf16x8 bfr = *(bf16x8*)&Xt[j * 16 + (lane & 15)][kc];
                acc[j] = __builtin_amdgcn_mfma_f32_16x16x32_bf16(af, bfr, acc[j], 0, 0, 0);
            }
        }
        __syncthreads();
    }

    const int col = lane & 15, quad = lane >> 4;
    float bias_v[4];
    #pragma unroll
    for (int r = 0; r < 4; r++) bias_v[r] = bias[w * 16 + quad * 4 + r];
    #pragma unroll
    for (int j = 0; j < 8; j++) {
        #pragma unroll
        for (int r = 0; r < 4; r++) {
            int m = w * 16 + quad * 4 + r;
            outp[(size_t)m * T_ + t0 + j * 16 + col] = acc[j][r] + bias_v[r];
        }
    }
}

// ---------------------------------------------------------------------------
// BatchNorm stats (unchanged)
// ---------------------------------------------------------------------------
__global__ __launch_bounds__(256) void bnstats_kernel(
    const float* __restrict__ q_raw, const float* __restrict__ v_raw,
    const float* __restrict__ gq, const float* __restrict__ betaq,
    const float* __restrict__ gv, const float* __restrict__ betav,
    float* __restrict__ qprm, float* __restrict__ vprm)
{
    __shared__ float rs[256], rq[256];
    const int tid = threadIdx.x, ch = blockIdx.x;
    const float* src; int C, c; float gamma, beta; float *scl, *shf;
    if (ch < K_) { c = ch;      src = q_raw; C = K_; gamma = gq[c]; beta = betaq[c]; scl = qprm + c; shf = qprm + K_ + c; }
    else         { c = ch - K_; src = v_raw; C = V_; gamma = gv[c]; beta = betav[c]; scl = vprm + c; shf = vprm + V_ + c; }
    float s = 0.f, sq = 0.f;
    for (int i = tid; i < B_ * T_; i += 256) {
        int b = i >> 10, t = i & (T_ - 1);
        float v = src[((size_t)b * C + c) * T_ + t];
        s += v; sq += v * v;
    }
    rs[tid] = s; rq[tid] = sq; __syncthreads();
    for (int st = 128; st > 0; st >>= 1) {
        if (tid < st) { rs[tid] += rs[tid + st]; rq[tid] += rq[tid + st]; }
        __syncthreads();
    }
    if (tid == 0) {
        float mean = rs[0] * (1.f / (B_ * T_));
        float var  = rq[0] * (1.f / (B_ * T_)) - mean * mean;
        float sc = gamma * rsqrtf(var + EPS_);
        *scl = sc; *shf = beta - mean * sc;
    }
}

// ---------------------------------------------------------------------------
// Softmax over T (unchanged)
// ---------------------------------------------------------------------------
__global__ __launch_bounds__(256) void softmax_kernel(float* __restrict__ k_buf)
{
    __shared__ float red[256];
    const int tid = threadIdx.x;
    float4* row = (float4*)(k_buf + (size_t)blockIdx.x * T_);
    float4 v = row[tid];
    float mx = fmaxf(fmaxf(v.x, v.y), fmaxf(v.z, v.w));
    red[tid] = mx; __syncthreads();
    for (int st = 128; st > 0; st >>= 1) {
        if (tid < st) red[tid] = fmaxf(red[tid], red[tid + st]);
        __syncthreads();
    }
    mx = red[0]; __syncthreads();
    float4 e;
    e.x = __expf(v.x - mx); e.y = __expf(v.y - mx);
    e.z = __expf(v.z - mx); e.w = __expf(v.w - mx);
    red[tid] = e.x + e.y + e.z + e.w; __syncthreads();
    for (int st = 128; st > 0; st >>= 1) {
        if (tid < st) red[tid] += red[tid + st];
        __syncthreads();
    }
    float inv = 1.f / red[0];
    e.x *= inv; e.y *= inv; e.z *= inv; e.w *= inv;
    row[tid] = e;
}

// ---------------------------------------------------------------------------
// Zero-fill for cl (graph-capture-safe)
// ---------------------------------------------------------------------------
__global__ __launch_bounds__(256) void zero_kernel(float4* __restrict__ p)
{
    p[blockIdx.x * 256 + threadIdx.x] = make_float4(0.f, 0.f, 0.f, 0.f);
}

// ---------------------------------------------------------------------------
// lambda2 (unchanged from R3): cl[b,k,v] += sum_t nk*v_raw, t-split atomics
// ---------------------------------------------------------------------------
__global__ __launch_bounds__(256) void lambda_kernel2(
    const float* __restrict__ k_buf, const float* __restrict__ v_raw,
    float* __restrict__ cl)
{
    __shared__ __align__(16) float nks[K_][68];   // [k][t]
    __shared__ __align__(16) float vls[64][68];   // [t][v]
    const int tid = threadIdx.x;
    const int b = blockIdx.z, v0 = blockIdx.y * 64, t0 = blockIdx.x * 64;

    {
        const int r = tid >> 2, q = tid & 3;
        const float* nrow = k_buf + ((size_t)b * K_ + r) * T_ + t0;
        const float* vrow = v_raw + ((size_t)b * V_ + v0 + r) * T_ + t0;
        #pragma unroll
        for (int i = 0; i < 4; i++) {
            int c4 = q + 4 * i;
            float4 g = *(const float4*)(nrow + 4 * c4);
            *(float4*)&nks[r][4 * c4] = g;
            float4 h = *(const float4*)(vrow + 4 * c4);
            vls[4 * c4 + 0][r] = h.x; vls[4 * c4 + 1][r] = h.y;
            vls[4 * c4 + 2][r] = h.z; vls[4 * c4 + 3][r] = h.w;
        }
    }
    __syncthreads();

    const int tv = tid & 15, tk = tid >> 4;
    float4 acc[4];
    #pragma unroll
    for (int i = 0; i < 4; i++) acc[i] = make_float4(0.f, 0.f, 0.f, 0.f);

    for (int tt = 0; tt < 16; tt++) {
        float4 w0 = *(float4*)&vls[4 * tt + 0][4 * tv];
        float4 w1 = *(float4*)&vls[4 * tt + 1][4 * tv];
        float4 w2 = *(float4*)&vls[4 * tt + 2][4 * tv];
        float4 w3 = *(float4*)&vls[4 * tt + 3][4 * tv];
        #pragma unroll
        for (int i = 0; i < 4; i++) {
            float4 n = *(float4*)&nks[4 * tk + i][4 * tt];
            acc[i] += w0 * n.x + w1 * n.y + w2 * n.z + w3 * n.w;
        }
    }
    #pragma unroll
    for (int i = 0; i < 4; i++) {
        float* ap = (float*)&acc[i];
        #pragma unroll
        for (int j = 0; j < 4; j++)
            atomicAdd(&cl[((size_t)b * K_ + 4 * tk + i) * V_ + v0 + 4 * tv + j], ap[j]);
    }
}

// ---------------------------------------------------------------------------
// qp2 (unchanged)
// ---------------------------------------------------------------------------
__global__ __launch_bounds__(256) void qp_kernel2(
    const float* __restrict__ q_raw, const float* __restrict__ pos_w,
    const float* __restrict__ pos_b, const float* __restrict__ qprm,
    float* __restrict__ qp)
{
    __shared__ float pw[K_ * KS_];
    __shared__ float pb[K_];
    __shared__ float red[4][64][KS_ + 2];
    const int tid = threadIdx.x;
    for (int i = tid; i < K_ * KS_; i += 256) pw[i] = pos_w[i];
    if (tid < K_) pb[tid] = pos_b[tid];
    __syncthreads();
    const int b = blockIdx.x >> 4, t0 = (blockIdx.x & 15) * 64;
    const int tl = tid & 63, kq = tid >> 6;
    float accum[KS_ + 1];
    #pragma unroll
    for (int s = 0; s <= KS_; s++) accum[s] = 0.f;
    for (int kk = 0; kk < 16; kk++) {
        int k = kq * 16 + kk;
        float qv = q_raw[((size_t)b * K_ + k) * T_ + t0 + tl] * qprm[k] + qprm[K_ + k];
        #pragma unroll
        for (int s = 0; s < KS_; s++) accum[s] += qv * pw[k * KS_ + s];
        accum[KS_] += qv * pb[k];
    }
    #pragma unroll
    for (int s = 0; s <= KS_; s++) red[kq][tl][s] = accum[s];
    __syncthreads();
    for (int idx = tid; idx < 64 * (KS_ + 1); idx += 256) {
        int t = idx / (KS_ + 1), s = idx % (KS_ + 1);
        float v = red[0][t][s] + red[1][t][s] + red[2][t][s] + red[3][t][s];
        qp[((size_t)b * (KS_ + 1) + s) * T_ + t0 + t] = v;
    }
}

// ---------------------------------------------------------------------------
// out2 (unchanged): out[b,v,t] = qb + sum_k qbn*clb + sum_s qp*vbn
// ---------------------------------------------------------------------------
__global__ __launch_bounds__(256) void out_kernel2(
    const float* __restrict__ q_raw, const float* __restrict__ v_raw,
    const float* __restrict__ cl, const float* __restrict__ qp,
    const float* __restrict__ qprm, const float* __restrict__ vprm,
    float* __restrict__ out)
{
    __shared__ __align__(16) float qs[K_][68];        // [k][t]
    __shared__ __align__(16) float clb[K_][68];       // [k][v]
    __shared__ __align__(16) float qps[KS_ + 1][68];  // [s][t]
    __shared__ __align__(16) float vs2[64][90];       // [v][c], c0 = t0-11
    const int tid = threadIdx.x;
    const int b = blockIdx.z, v0 = blockIdx.y * 64, t0 = blockIdx.x * 64;

    {
        const int k = tid >> 2, q = tid & 3;
        const float s = qprm[k], h = qprm[K_ + k];
        const float* qrow = q_raw + ((size_t)b * K_ + k) * T_ + t0;
        const float* crow = cl + ((size_t)b * K_ + k) * V_ + v0;
        #pragma unroll
        for (int i = 0; i < 4; i++) {
            int c4 = q + 4 * i;
            float4 g = *(const float4*)(qrow + 4 * c4);
            float4 o = make_float4(g.x * s + h, g.y * s + h, g.z * s + h, g.w * s + h);
            *(float4*)&qs[k][4 * c4] = o;
            float4 c  = *(const float4*)(crow + 4 * c4);
            float4 sv = *(const float4*)&vprm[v0 + 4 * c4];
            float4 hv = *(const float4*)&vprm[V_ + v0 + 4 * c4];
            float4 cb = make_float4(c.x * sv.x + hv.x, c.y * sv.y + hv.y,
                                    c.z * sv.z + hv.z, c.w * sv.w + hv.w);
            *(float4*)&clb[k][4 * c4] = cb;
        }
    }
    for (int idx = tid; idx < (KS_ + 1) * 16; idx += 256) {
        int s = idx >> 4, c4 = idx & 15;
        *(float4*)&qps[s][4 * c4] =
            *(const float4*)(qp + ((size_t)b * (KS_ + 1) + s) * T_ + t0 + 4 * c4);
    }
    {
        const int v = tid >> 2, q = tid & 3;
        const float sv = vprm[v0 + v], hv = vprm[V_ + v0 + v];
        const float* vrow = v_raw + ((size_t)b * V_ + v0 + v) * T_;
        #pragma unroll
        for (int i = 0; i < 22; i++) {
            int c = q + 4 * i;
            if (c < 86) {
                int t = t0 - 11 + c;
                vs2[v][c] = (t >= 0 && t < T_) ? vrow[t] * sv + hv : 0.f;
            }
        }
    }
    __syncthreads();

    const int tx = tid & 15, ty = tid >> 4;
    float4 acc[4];
    #pragma unroll
    for (int i = 0; i < 4; i++) acc[i] = make_float4(0.f, 0.f, 0.f, 0.f);

    for (int k = 0; k < K_; k++) {
        float4 cv = *(float4*)&clb[k][4 * ty];
        acc[0] += cv * qs[k][tx];
        acc[1] += cv * qs[k][tx + 16];
        acc[2] += cv * qs[k][tx + 32];
        acc[3] += cv * qs[k][tx + 48];
    }
    #pragma unroll 1
    for (int s = 0; s < KS_; s++) {
        #pragma unroll
        for (int i = 0; i < 4; i++) {
            float qpl = qps[s][tx + 16 * i];
            int c = tx + 16 * i + s;
            float4 vv = make_float4(vs2[4 * ty + 0][c], vs2[4 * ty + 1][c],
                                    vs2[4 * ty + 2][c], vs2[4 * ty + 3][c]);
            acc[i] += vv * qpl;
        }
    }
    #pragma unroll
    for (int i = 0; i < 4; i++) {
        float qb = qps[KS_][tx + 16 * i];
        float* ap = (float*)&acc[i];
        #pragma unroll
        for (int j = 0; j < 4; j++)
            out[((size_t)b * V_ + v0 + 4 * ty + j) * T_ + t0 + tx + 16 * i] = ap[j] + qb;
    }
}

extern "C" void kernel_launch(void* const* d_in, const int* in_sizes, int n_in,
                              void* d_out, int out_size, void* d_ws, size_t ws_size,
                              hipStream_t stream)
{
    const float* x     = (const float*)d_in[0];
    const float* ctx   = (const float*)d_in[1];
    const float* Wq    = (const float*)d_in[2];
    const float* bq    = (const float*)d_in[3];
    const float* Wk    = (const float*)d_in[4];
    const float* bk    = (const float*)d_in[5];
    const float* Wv    = (const float*)d_in[6];
    const float* bv    = (const float*)d_in[7];
    const float* gq    = (const float*)d_in[8];
    const float* betaq = (const float*)d_in[9];
    const float* gv    = (const float*)d_in[10];
    const float* betav = (const float*)d_in[11];
    const float* pos_w = (const float*)d_in[12];
    const float* pos_b = (const float*)d_in[13];
    float* out = (float*)d_out;

    float* ws    = (float*)d_ws;
    float* q_raw = ws;                                  // B*K*T
    float* k_buf = q_raw + (size_t)B_ * K_ * T_;        // B*K*T
    float* v_raw = k_buf + (size_t)B_ * K_ * T_;        // B*V*T
    float* cl    = v_raw + (size_t)B_ * V_ * T_;        // B*K*V
    float* qp    = cl + (size_t)B_ * K_ * V_;           // B*24*T
    float* qprm  = qp + (size_t)B_ * (KS_ + 1) * T_;    // 2*K
    float* vprm  = qprm + 2 * K_;                       // 2*V

    proj_mfma<<<dim3(T_ / 128, 6, B_), 256, 0, stream>>>(
        x, ctx, Wq, bq, Wk, bk, Wv, bv, q_raw, k_buf, v_raw);
    bnstats_kernel<<<dim3(K_ + V_), 256, 0, stream>>>(
        q_raw, v_raw, gq, betaq, gv, betav, qprm, vprm);
    softmax_kernel<<<dim3(B_ * K_), 256, 0, stream>>>(k_buf);
    zero_kernel<<<dim3(B_ * K_ * V_ / 1024), 256, 0, stream>>>((float4*)cl);
    lambda_kernel2<<<dim3(T_ / 64, V_ / 64, B_), 256, 0, stream>>>(k_buf, v_raw, cl);
    qp_kernel2<<<dim3(B_ * T_ / 64), 256, 0, stream>>>(
        q_raw, pos_w, pos_b, qprm, qp);
    out_kernel2<<<dim3(T_ / 64, V_ / 64, B_), 256, 0, stream>>>(
        q_raw, v_raw, cl, qp, qprm, vprm, out);
}

// Round 5
// 186.349 us; speedup vs baseline: 1.4710x; 1.0298x over previous
//
#include <hip/hip_runtime.h>
#include <math.h>

#define B_ 8
#define CIN_ 512
#define K_ 64
#define V_ 256
#define T_ 1024
#define KS_ 23
#define EPS_ 1e-5f

typedef __attribute__((ext_vector_type(8))) short bf16x8;
typedef __attribute__((ext_vector_type(4))) float f32x4;

__device__ __forceinline__ unsigned short f2bf(float f) {
    union { float f; unsigned u; } x; x.f = f;
    unsigned r = x.u + 0x7fffu + ((x.u >> 16) & 1u);   // RNE
    return (unsigned short)(r >> 16);
}
__device__ __forceinline__ float bf2f(unsigned short h) {
    union { unsigned u; float f; } x; x.u = ((unsigned)h) << 16;
    return x.f;
}

// ---------------------------------------------------------------------------
// cvtT: src[b][c][t] f32 -> dst[b][t][c] bf16.  64x64 tiles via LDS.
// z: b = z&7, which = z>>3 (0: x->xT, 1: ctx->cT)
// ---------------------------------------------------------------------------
__global__ __launch_bounds__(256) void cvtT_kernel(
    const float* __restrict__ x, const float* __restrict__ ctx,
    unsigned short* __restrict__ xT, unsigned short* __restrict__ cT)
{
    __shared__ unsigned short sh[64][72];
    const int tid = threadIdx.x;
    const int t0 = blockIdx.x * 64, c0 = blockIdx.y * 64;
    const int b = blockIdx.z & 7, which = blockIdx.z >> 3;
    const float* src = which ? ctx : x;
    unsigned short* dst = which ? cT : xT;

    const int cl = tid >> 2, qq = tid & 3;
    const float* row = src + ((size_t)b * CIN_ + c0 + cl) * T_ + t0 + qq * 16;
    #pragma unroll
    for (int u = 0; u < 4; u++) {
        float4 f = *(const float4*)(row + 4 * u);
        sh[qq * 16 + 4 * u + 0][cl] = f2bf(f.x);
        sh[qq * 16 + 4 * u + 1][cl] = f2bf(f.y);
        sh[qq * 16 + 4 * u + 2][cl] = f2bf(f.z);
        sh[qq * 16 + 4 * u + 3][cl] = f2bf(f.w);
    }
    __syncthreads();
    const int tl = tid >> 2;
    unsigned short* orow = dst + ((size_t)b * T_ + t0 + tl) * CIN_ + c0 + qq * 16;
    *(bf16x8*)(orow)     = *(bf16x8*)&sh[tl][qq * 16];
    *(bf16x8*)(orow + 8) = *(bf16x8*)&sh[tl][qq * 16 + 8];
}

// ---------------------------------------------------------------------------
// prew: convert Wq|Wk|Wv fp32 -> bf16 (concatenated, layouts preserved).
// ---------------------------------------------------------------------------
__global__ __launch_bounds__(256) void prew_kernel(
    const float* __restrict__ Wq, const float* __restrict__ Wk,
    const float* __restrict__ Wv, unsigned short* __restrict__ Wb)
{
    const int i4 = blockIdx.x * 256 + threadIdx.x;   // float4 index
    const int n1 = K_ * CIN_ / 4, n2 = 2 * K_ * CIN_ / 4;
    const float* src; int off;
    if (i4 < n1)      { src = Wq; off = i4; }
    else if (i4 < n2) { src = Wk; off = i4 - n1; }
    else              { src = Wv; off = i4 - n2; }
    float4 f = ((const float4*)src)[off];
    ushort4 h;
    h.x = f2bf(f.x); h.y = f2bf(f.y); h.z = f2bf(f.z); h.w = f2bf(f.w);
    *(ushort4*)(Wb + (size_t)i4 * 4) = h;
}

// ---------------------------------------------------------------------------
// proj_mfma2: out[b,m,t] = bias[m] + sum_c W[m,c]*in[b,c,t].  All-bf16 LDS,
// no converts in the K-loop.  yb: 0=q (also emits qT bf16), 1=k, 2..5=v.
// 64m x 128t tile, BK=64.
// ---------------------------------------------------------------------------
__global__ __launch_bounds__(256) void proj_mfma2(
    const unsigned short* __restrict__ xT, const unsigned short* __restrict__ cT,
    const unsigned short* __restrict__ Wb,
    const float* __restrict__ bq, const float* __restrict__ bk,
    const float* __restrict__ bv,
    float* __restrict__ q_raw, float* __restrict__ k_buf, float* __restrict__ v_raw,
    unsigned short* __restrict__ qT)
{
    __shared__ unsigned short Wt[64][72];
    __shared__ unsigned short Xt[128][72];
    const int tid = threadIdx.x;
    const int b = blockIdx.z, t0 = blockIdx.x * 128, yb = blockIdx.y;

    const unsigned short* in; const unsigned short* W; const float* bias; float* outp;
    if (yb == 0)      { in = xT; W = Wb;               bias = bq; outp = q_raw + (size_t)b * K_ * T_; }
    else if (yb == 1) { in = cT; W = Wb + K_ * CIN_;   bias = bk; outp = k_buf + (size_t)b * K_ * T_; }
    else { int m0 = (yb - 2) * 64; in = cT;
           W = Wb + 2 * K_ * CIN_ + (size_t)m0 * CIN_; bias = bv + m0;
           outp = v_raw + ((size_t)b * V_ + m0) * T_; }

    const int lane = tid & 63, w = tid >> 6;
    const int col = lane & 15, quad = lane >> 4;
    const int wm = tid >> 2, wp = tid & 3;     // W staging
    const int xt = tid >> 1, xh = tid & 1;     // X staging

    f32x4 acc[8];
    #pragma unroll
    for (int j = 0; j < 8; j++) acc[j] = (f32x4){0.f, 0.f, 0.f, 0.f};

    for (int c0 = 0; c0 < CIN_; c0 += 64) {
        {
            const unsigned short* ws = W + (size_t)wm * CIN_ + c0 + wp * 16;
            *(bf16x8*)&Wt[wm][wp * 16]     = *(const bf16x8*)(ws);
            *(bf16x8*)&Wt[wm][wp * 16 + 8] = *(const bf16x8*)(ws + 8);
            const unsigned short* xs = in + ((size_t)b * T_ + t0 + xt) * CIN_ + c0 + xh * 32;
            #pragma unroll
            for (int u = 0; u < 4; u++)
                *(bf16x8*)&Xt[xt][xh * 32 + 8 * u] = *(const bf16x8*)(xs + 8 * u);
        }
        __syncthreads();
        #pragma unroll
        for (int ks = 0; ks < 2; ks++) {
            const int kc = ks * 32 + quad * 8;
            bf16x8 af = *(bf16x8*)&Wt[w * 16 + col][kc];
            #pragma unroll
            for (int j = 0; j < 8; j++) {
                bf16x8 bfr = *(bf16x8*)&Xt[j * 16 + col][kc];
                acc[j] = __builtin_amdgcn_mfma_f32_16x16x32_bf16(af, bfr, acc[j], 0, 0, 0);
            }
        }
        __syncthreads();
    }

    float bias_v[4];
    #pragma unroll
    for (int r = 0; r < 4; r++) bias_v[r] = bias[w * 16 + quad * 4 + r];
    #pragma unroll
    for (int j = 0; j < 8; j++) {
        float o[4];
        #pragma unroll
        for (int r = 0; r < 4; r++) {
            o[r] = acc[j][r] + bias_v[r];
            outp[(size_t)(w * 16 + quad * 4 + r) * T_ + t0 + j * 16 + col] = o[r];
        }
        if (yb == 0) {
            ushort4 h;
            h.x = f2bf(o[0]); h.y = f2bf(o[1]); h.z = f2bf(o[2]); h.w = f2bf(o[3]);
            *(ushort4*)(qT + ((size_t)b * T_ + t0 + j * 16 + col) * K_ + w * 16 + quad * 4) = h;
        }
    }
}

// ---------------------------------------------------------------------------
// BatchNorm stats (unchanged)
// ---------------------------------------------------------------------------
__global__ __launch_bounds__(256) void bnstats_kernel(
    const float* __restrict__ q_raw, const float* __restrict__ v_raw,
    const float* __restrict__ gq, const float* __restrict__ betaq,
    const float* __restrict__ gv, const float* __restrict__ betav,
    float* __restrict__ qprm, float* __restrict__ vprm)
{
    __shared__ float rs[256], rq[256];
    const int tid = threadIdx.x, ch = blockIdx.x;
    const float* src; int C, c; float gamma, beta; float *scl, *shf;
    if (ch < K_) { c = ch;      src = q_raw; C = K_; gamma = gq[c]; beta = betaq[c]; scl = qprm + c; shf = qprm + K_ + c; }
    else         { c = ch - K_; src = v_raw; C = V_; gamma = gv[c]; beta = betav[c]; scl = vprm + c; shf = vprm + V_ + c; }
    float s = 0.f, sq = 0.f;
    for (int i = tid; i < B_ * T_; i += 256) {
        int b = i >> 10, t = i & (T_ - 1);
        float v = src[((size_t)b * C + c) * T_ + t];
        s += v; sq += v * v;
    }
    rs[tid] = s; rq[tid] = sq; __syncthreads();
    for (int st = 128; st > 0; st >>= 1) {
        if (tid < st) { rs[tid] += rs[tid + st]; rq[tid] += rq[tid + st]; }
        __syncthreads();
    }
    if (tid == 0) {
        float mean = rs[0] * (1.f / (B_ * T_));
        float var  = rq[0] * (1.f / (B_ * T_)) - mean * mean;
        float sc = gamma * rsqrtf(var + EPS_);
        *scl = sc; *shf = beta - mean * sc;
    }
}

// ---------------------------------------------------------------------------
// Softmax over T (unchanged)
// ---------------------------------------------------------------------------
__global__ __launch_bounds__(256) void softmax_kernel(float* __restrict__ k_buf)
{
    __shared__ float red[256];
    const int tid = threadIdx.x;
    float4* row = (float4*)(k_buf + (size_t)blockIdx.x * T_);
    float4 v = row[tid];
    float mx = fmaxf(fmaxf(v.x, v.y), fmaxf(v.z, v.w));
    red[tid] = mx; __syncthreads();
    for (int st = 128; st > 0; st >>= 1) {
        if (tid < st) red[tid] = fmaxf(red[tid], red[tid + st]);
        __syncthreads();
    }
    mx = red[0]; __syncthreads();
    float4 e;
    e.x = __expf(v.x - mx); e.y = __expf(v.y - mx);
    e.z = __expf(v.z - mx); e.w = __expf(v.w - mx);
    red[tid] = e.x + e.y + e.z + e.w; __syncthreads();
    for (int st = 128; st > 0; st >>= 1) {
        if (tid < st) red[tid] += red[tid + st];
        __syncthreads();
    }
    float inv = 1.f / red[0];
    e.x *= inv; e.y *= inv; e.z *= inv; e.w *= inv;
    row[tid] = e;
}

__global__ __launch_bounds__(256) void zero_kernel(float4* __restrict__ p)
{
    p[blockIdx.x * 256 + threadIdx.x] = make_float4(0.f, 0.f, 0.f, 0.f);
}

// ---------------------------------------------------------------------------
// lambda2 (unchanged): cl[b,k,v] += sum_t nk*v_raw  (t-split atomics)
// ---------------------------------------------------------------------------
__global__ __launch_bounds__(256) void lambda_kernel2(
    const float* __restrict__ k_buf, const float* __restrict__ v_raw,
    float* __restrict__ cl)
{
    __shared__ __align__(16) float nks[K_][68];
    __shared__ __align__(16) float vls[64][68];
    const int tid = threadIdx.x;
    const int b = blockIdx.z, v0 = blockIdx.y * 64, t0 = blockIdx.x * 64;
    {
        const int r = tid >> 2, q = tid & 3;
        const float* nrow = k_buf + ((size_t)b * K_ + r) * T_ + t0;
        const float* vrow = v_raw + ((size_t)b * V_ + v0 + r) * T_ + t0;
        #pragma unroll
        for (int i = 0; i < 4; i++) {
            int c4 = q + 4 * i;
            float4 g = *(const float4*)(nrow + 4 * c4);
            *(float4*)&nks[r][4 * c4] = g;
            float4 h = *(const float4*)(vrow + 4 * c4);
            vls[4 * c4 + 0][r] = h.x; vls[4 * c4 + 1][r] = h.y;
            vls[4 * c4 + 2][r] = h.z; vls[4 * c4 + 3][r] = h.w;
        }
    }
    __syncthreads();
    const int tv = tid & 15, tk = tid >> 4;
    float4 acc[4];
    #pragma unroll
    for (int i = 0; i < 4; i++) acc[i] = make_float4(0.f, 0.f, 0.f, 0.f);
    for (int tt = 0; tt < 16; tt++) {
        float4 w0 = *(float4*)&vls[4 * tt + 0][4 * tv];
        float4 w1 = *(float4*)&vls[4 * tt + 1][4 * tv];
        float4 w2 = *(float4*)&vls[4 * tt + 2][4 * tv];
        float4 w3 = *(float4*)&vls[4 * tt + 3][4 * tv];
        #pragma unroll
        for (int i = 0; i < 4; i++) {
            float4 n = *(float4*)&nks[4 * tk + i][4 * tt];
            acc[i] += w0 * n.x + w1 * n.y + w2 * n.z + w3 * n.w;
        }
    }
    #pragma unroll
    for (int i = 0; i < 4; i++) {
        float* ap = (float*)&acc[i];
        #pragma unroll
        for (int j = 0; j < 4; j++)
            atomicAdd(&cl[((size_t)b * K_ + 4 * tk + i) * V_ + v0 + 4 * tv + j], ap[j]);
    }
}

// ---------------------------------------------------------------------------
// prep_cl: clb = cl*vs+vh;  clb2[b][v][k] = bf16(clb*qs[k]);
//          hterm[b][v] = sum_k qh[k]*clb.
// ---------------------------------------------------------------------------
__global__ __launch_bounds__(256) void prep_cl_kernel(
    const float* __restrict__ cl, const float* __restrict__ qprm,
    const float* __restrict__ vprm, unsigned short* __restrict__ clb2,
    float* __restrict__ hterm)
{
    __shared__ float red[4][64];
    const int tid = threadIdx.x;
    const int b = blockIdx.y, v0 = blockIdx.x * 64;
    const int vl = tid & 63, kq = tid >> 6;
    const float vsv = vprm[v0 + vl], vhv = vprm[V_ + v0 + vl];
    float h = 0.f;
    for (int kk = 0; kk < 16; kk++) {
        int k = kq * 16 + kk;
        float c = cl[((size_t)b * K_ + k) * V_ + v0 + vl];
        float clbv = c * vsv + vhv;
        h += qprm[K_ + k] * clbv;
        clb2[((size_t)b * V_ + v0 + vl) * K_ + k] = f2bf(clbv * qprm[k]);
    }
    red[kq][vl] = h;
    __syncthreads();
    if (tid < 64)
        hterm[(size_t)b * V_ + v0 + tid] =
            red[0][tid] + red[1][tid] + red[2][tid] + red[3][tid];
}

// ---------------------------------------------------------------------------
// qp3: qpT[b][t][s] (s<23) = sum_k qbn*pw[k,s]; s=23 slot = qbn . pos_b.
// BN folded: sum_k q*(qs*pw) + const_s.  Reads contiguous bf16 qT rows.
// ---------------------------------------------------------------------------
__global__ __launch_bounds__(256) void qp_kernel3(
    const unsigned short* __restrict__ qT, const float* __restrict__ pos_w,
    const float* __restrict__ pos_b, const float* __restrict__ qprm,
    float* __restrict__ qpT)
{
    __shared__ float pws[K_][24];
    __shared__ float consts[24];
    __shared__ float red[8][32][26];
    const int tid = threadIdx.x;
    for (int idx = tid; idx < K_ * 24; idx += 256) {
        int k = idx / 24, s = idx % 24;
        pws[k][s] = qprm[k] * (s < KS_ ? pos_w[k * KS_ + s] : pos_b[k]);
    }
    if (tid < 24) {
        float cs = 0.f;
        for (int k = 0; k < K_; k++)
            cs += qprm[K_ + k] * (tid < KS_ ? pos_w[k * KS_ + tid] : pos_b[k]);
        consts[tid] = cs;
    }
    __syncthreads();
    const int b = blockIdx.x >> 5, t0 = (blockIdx.x & 31) * 32;
    const int lt = tid & 31, ko = tid >> 5;
    float qf[8];
    {
        bf16x8 qv = *(const bf16x8*)(qT + ((size_t)b * T_ + t0 + lt) * K_ + ko * 8);
        #pragma unroll
        for (int i = 0; i < 8; i++) qf[i] = bf2f((unsigned short)qv[i]);
    }
    float accum[24];
    #pragma unroll
    for (int s = 0; s < 24; s++) accum[s] = 0.f;
    #pragma unroll
    for (int kk = 0; kk < 8; kk++) {
        float q = qf[kk];
        #pragma unroll
        for (int s = 0; s < 24; s++) accum[s] += q * pws[ko * 8 + kk][s];
    }
    #pragma unroll
    for (int s = 0; s < 24; s++) red[ko][lt][s] = accum[s];
    __syncthreads();
    for (int idx = tid; idx < 32 * 24; idx += 256) {
        int t = idx / 24, s = idx % 24;
        float v = consts[s];
        #pragma unroll
        for (int o = 0; o < 8; o++) v += red[o][t][s];
        qpT[((size_t)b * T_ + t0 + t) * 28 + s] = v;
    }
}

// ---------------------------------------------------------------------------
// out3: out[b,v,t] = MFMA(clb2, qT) + hterm[v] + qb[t]
//                  + sum_s qpT[t][s]*vbn[v][t+s-11]
// 64t x 64v tile.  MFMA D[m=v][n=t]; conv vectorized over 4 consecutive v.
// ---------------------------------------------------------------------------
__global__ __launch_bounds__(256) void out_kernel3(
    const unsigned short* __restrict__ qT, const unsigned short* __restrict__ clb2,
    const float* __restrict__ hterm, const float* __restrict__ qpT,
    const float* __restrict__ v_raw, const float* __restrict__ vprm,
    float* __restrict__ out)
{
    __shared__ unsigned short qTt[64][72];   // [t][k]
    __shared__ unsigned short clv[64][72];   // [v][k]
    __shared__ float vs2T[88][68];           // [c][v], global t = t0 + c - 11
    __shared__ float qpt[64][28];            // [t][s], s=23 is qb
    __shared__ float hvs[64];
    const int tid = threadIdx.x;
    const int b = blockIdx.z, v0 = blockIdx.y * 64, t0 = blockIdx.x * 64;

    {   // qTt + clv staging (b128 copies)
        const int rl = tid >> 2, part = tid & 3;
        const unsigned short* qs = qT + ((size_t)b * T_ + t0 + rl) * K_ + part * 16;
        *(bf16x8*)&qTt[rl][part * 16]     = *(const bf16x8*)(qs);
        *(bf16x8*)&qTt[rl][part * 16 + 8] = *(const bf16x8*)(qs + 8);
        const unsigned short* cs = clb2 + ((size_t)b * V_ + v0 + rl) * K_ + part * 16;
        *(bf16x8*)&clv[rl][part * 16]     = *(const bf16x8*)(cs);
        *(bf16x8*)&clv[rl][part * 16 + 8] = *(const bf16x8*)(cs + 8);
    }
    {   // qpt flat copy (rows contiguous in global)
        const float4* src = (const float4*)(qpT + ((size_t)b * T_ + t0) * 28);
        float4* dst = (float4*)&qpt[0][0];
        for (int idx = tid; idx < 64 * 28 / 4; idx += 256) dst[idx] = src[idx];
    }
    if (tid < 64) hvs[tid] = hterm[(size_t)b * V_ + v0 + tid];
    {   // vs2T: BN'd v window, transposed [c][v]
        const int vl = tid >> 2, qq = tid & 3;
        const float vsv = vprm[v0 + vl], vhv = vprm[V_ + v0 + vl];
        const float* vrow = v_raw + ((size_t)b * V_ + v0 + vl) * T_;
        #pragma unroll
        for (int i = 0; i < 22; i++) {
            int c = qq + 4 * i;
            if (c < 86) {
                int t = t0 + c - 11;
                vs2T[c][vl] = (t >= 0 && t < T_) ? vrow[t] * vsv + vhv : 0.f;
            }
        }
    }
    __syncthreads();

    const int lane = tid & 63, w = tid >> 6;
    const int col = lane & 15, quad = lane >> 4;

    f32x4 acc[4];   // acc[tf]: D[v = v0 + w*16+quad*4+r][t = t0 + tf*16+col]
    #pragma unroll
    for (int tf = 0; tf < 4; tf++) acc[tf] = (f32x4){0.f, 0.f, 0.f, 0.f};

    #pragma unroll
    for (int ks = 0; ks < 2; ks++) {
        const int kc = ks * 32 + quad * 8;
        bf16x8 af = *(bf16x8*)&clv[w * 16 + col][kc];
        #pragma unroll
        for (int tf = 0; tf < 4; tf++) {
            bf16x8 bq = *(bf16x8*)&qTt[tf * 16 + col][kc];
            acc[tf] = __builtin_amdgcn_mfma_f32_16x16x32_bf16(af, bq, acc[tf], 0, 0, 0);
        }
    }

    const int vb = w * 16 + quad * 4;
    float4 hv4 = *(float4*)&hvs[vb];
    #pragma unroll
    for (int tf = 0; tf < 4; tf++) {
        const int lt = tf * 16 + col;
        float qv[24];
        #pragma unroll
        for (int u = 0; u < 6; u++)
            *(float4*)&qv[4 * u] = *(float4*)&qpt[lt][4 * u];
        float4 a; a.x = acc[tf][0]; a.y = acc[tf][1]; a.z = acc[tf][2]; a.w = acc[tf][3];
        #pragma unroll
        for (int s = 0; s < KS_; s++) {
            float4 wv = *(float4*)&vs2T[lt + s][vb];
            a.x += qv[s] * wv.x; a.y += qv[s] * wv.y;
            a.z += qv[s] * wv.z; a.w += qv[s] * wv.w;
        }
        float base = qv[23];
        a.x += base + hv4.x; a.y += base + hv4.y;
        a.z += base + hv4.z; a.w += base + hv4.w;
        float* ap = (float*)&a;
        #pragma unroll
        for (int r = 0; r < 4; r++)
            out[((size_t)b * V_ + v0 + vb + r) * T_ + t0 + lt] = ap[r];
    }
}

extern "C" void kernel_launch(void* const* d_in, const int* in_sizes, int n_in,
                              void* d_out, int out_size, void* d_ws, size_t ws_size,
                              hipStream_t stream)
{
    const float* x     = (const float*)d_in[0];
    const float* ctx   = (const float*)d_in[1];
    const float* Wq    = (const float*)d_in[2];
    const float* bq    = (const float*)d_in[3];
    const float* Wk    = (const float*)d_in[4];
    const float* bk    = (const float*)d_in[5];
    const float* Wv    = (const float*)d_in[6];
    const float* bv    = (const float*)d_in[7];
    const float* gq    = (const float*)d_in[8];
    const float* betaq = (const float*)d_in[9];
    const float* gv    = (const float*)d_in[10];
    const float* betav = (const float*)d_in[11];
    const float* pos_w = (const float*)d_in[12];
    const float* pos_b = (const float*)d_in[13];
    float* out = (float*)d_out;

    float* ws    = (float*)d_ws;
    float* q_raw = ws;                                   // 524288
    float* k_buf = q_raw + (size_t)B_ * K_ * T_;         // 524288
    float* v_raw = k_buf + (size_t)B_ * K_ * T_;         // 2097152
    float* cl    = v_raw + (size_t)B_ * V_ * T_;         // 131072
    float* qpT   = cl + (size_t)B_ * K_ * V_;            // B*T*28 = 229376
    float* hterm = qpT + (size_t)B_ * T_ * 28;           // 2048
    float* qprm  = hterm + (size_t)B_ * V_;              // 128
    float* vprm  = qprm + 2 * K_;                        // 512
    unsigned short* xT   = (unsigned short*)(vprm + 2 * V_);            // B*T*CIN sh
    unsigned short* cT   = xT + (size_t)B_ * T_ * CIN_;                 // B*T*CIN sh
    unsigned short* Wb   = cT + (size_t)B_ * T_ * CIN_;                 // 196608 sh
    unsigned short* qT   = Wb + (size_t)(2 * K_ + V_) * CIN_;           // B*T*K sh
    unsigned short* clb2 = qT + (size_t)B_ * T_ * K_;                   // B*V*K sh

    cvtT_kernel<<<dim3(T_ / 64, CIN_ / 64, 2 * B_), 256, 0, stream>>>(x, ctx, xT, cT);
    prew_kernel<<<dim3((2 * K_ + V_) * CIN_ / 1024), 256, 0, stream>>>(Wq, Wk, Wv, Wb);
    proj_mfma2<<<dim3(T_ / 128, 6, B_), 256, 0, stream>>>(
        xT, cT, Wb, bq, bk, bv, q_raw, k_buf, v_raw, qT);
    bnstats_kernel<<<dim3(K_ + V_), 256, 0, stream>>>(
        q_raw, v_raw, gq, betaq, gv, betav, qprm, vprm);
    softmax_kernel<<<dim3(B_ * K_), 256, 0, stream>>>(k_buf);
    zero_kernel<<<dim3(B_ * K_ * V_ / 1024), 256, 0, stream>>>((float4*)cl);
    lambda_kernel2<<<dim3(T_ / 64, V_ / 64, B_), 256, 0, stream>>>(k_buf, v_raw, cl);
    prep_cl_kernel<<<dim3(V_ / 64, B_), 256, 0, stream>>>(cl, qprm, vprm, clb2, hterm);
    qp_kernel3<<<dim3(B_ * T_ / 32), 256, 0, stream>>>(qT, pos_w, pos_b, qprm, qpT);
    out_kernel3<<<dim3(T_ / 64, V_ / 64, B_), 256, 0, stream>>>(
        qT, clb2, hterm, qpT, v_raw, vprm, out);
}

// Round 6
// 182.692 us; speedup vs baseline: 1.5005x; 1.0200x over previous
//
#include <hip/hip_runtime.h>
#include <math.h>

#define B_ 8
#define CIN_ 512
#define K_ 64
#define V_ 256
#define T_ 1024
#define KS_ 23
#define EPS_ 1e-5f

typedef __attribute__((ext_vector_type(8))) short bf16x8;
typedef __attribute__((ext_vector_type(4))) float f32x4;

__device__ __forceinline__ unsigned short f2bf(float f) {
    union { float f; unsigned u; } x; x.f = f;
    unsigned r = x.u + 0x7fffu + ((x.u >> 16) & 1u);   // RNE
    return (unsigned short)(r >> 16);
}
__device__ __forceinline__ float bf2f(unsigned short h) {
    union { unsigned u; float f; } x; x.u = ((unsigned)h) << 16;
    return x.f;
}

// ---------------------------------------------------------------------------
// zero: cl (B*K*V) + stat accumulators (640) — must precede proj & lambda.
// ---------------------------------------------------------------------------
__global__ __launch_bounds__(256) void zero_kernel(float4* __restrict__ p, int n4)
{
    int i = blockIdx.x * 256 + threadIdx.x;
    if (i < n4) p[i] = make_float4(0.f, 0.f, 0.f, 0.f);
}

// ---------------------------------------------------------------------------
// cvtT: src[b][c][t] f32 -> dst[b][t][c] bf16.  64x64 tiles via LDS.
// ---------------------------------------------------------------------------
__global__ __launch_bounds__(256) void cvtT_kernel(
    const float* __restrict__ x, const float* __restrict__ ctx,
    unsigned short* __restrict__ xT, unsigned short* __restrict__ cT)
{
    __shared__ unsigned short sh[64][72];
    const int tid = threadIdx.x;
    const int t0 = blockIdx.x * 64, c0 = blockIdx.y * 64;
    const int b = blockIdx.z & 7, which = blockIdx.z >> 3;
    const float* src = which ? ctx : x;
    unsigned short* dst = which ? cT : xT;

    const int cl = tid >> 2, qq = tid & 3;
    const float* row = src + ((size_t)b * CIN_ + c0 + cl) * T_ + t0 + qq * 16;
    #pragma unroll
    for (int u = 0; u < 4; u++) {
        float4 f = *(const float4*)(row + 4 * u);
        sh[qq * 16 + 4 * u + 0][cl] = f2bf(f.x);
        sh[qq * 16 + 4 * u + 1][cl] = f2bf(f.y);
        sh[qq * 16 + 4 * u + 2][cl] = f2bf(f.z);
        sh[qq * 16 + 4 * u + 3][cl] = f2bf(f.w);
    }
    __syncthreads();
    const int tl = tid >> 2;
    unsigned short* orow = dst + ((size_t)b * T_ + t0 + tl) * CIN_ + c0 + qq * 16;
    *(bf16x8*)(orow)     = *(bf16x8*)&sh[tl][qq * 16];
    *(bf16x8*)(orow + 8) = *(bf16x8*)&sh[tl][qq * 16 + 8];
}

// ---------------------------------------------------------------------------
// prew: Wq|Wk|Wv fp32 -> bf16 concatenated.
// ---------------------------------------------------------------------------
__global__ __launch_bounds__(256) void prew_kernel(
    const float* __restrict__ Wq, const float* __restrict__ Wk,
    const float* __restrict__ Wv, unsigned short* __restrict__ Wb)
{
    const int i4 = blockIdx.x * 256 + threadIdx.x;
    const int n1 = K_ * CIN_ / 4, n2 = 2 * K_ * CIN_ / 4;
    const float* src; int off;
    if (i4 < n1)      { src = Wq; off = i4; }
    else if (i4 < n2) { src = Wk; off = i4 - n1; }
    else              { src = Wv; off = i4 - n2; }
    float4 f = ((const float4*)src)[off];
    ushort4 h;
    h.x = f2bf(f.x); h.y = f2bf(f.y); h.z = f2bf(f.z); h.w = f2bf(f.w);
    *(ushort4*)(Wb + (size_t)i4 * 4) = h;
}

// ---------------------------------------------------------------------------
// proj_mfma3: bf16 MFMA projection + FUSED BN channel stats (atomics).
// yb: 0 = q -> qT bf16 only (no fp32 q buffer) + q stats
//     1 = k -> k_buf fp32 (no stats)
//     2..5 = v slices -> v_raw fp32 + v stats
// stat layout: [0:64) qsum, [64:128) qsq, [128:384) vsum, [384:640) vsq
// ---------------------------------------------------------------------------
__global__ __launch_bounds__(256) void proj_mfma3(
    const unsigned short* __restrict__ xT, const unsigned short* __restrict__ cT,
    const unsigned short* __restrict__ Wb,
    const float* __restrict__ bq, const float* __restrict__ bk,
    const float* __restrict__ bv,
    float* __restrict__ k_buf, float* __restrict__ v_raw,
    unsigned short* __restrict__ qT, float* __restrict__ stat)
{
    __shared__ unsigned short Wt[64][72];
    __shared__ unsigned short Xt[128][72];
    const int tid = threadIdx.x;
    const int b = blockIdx.z, t0 = blockIdx.x * 128, yb = blockIdx.y;

    const unsigned short* in; const unsigned short* W; const float* bias;
    float* outp = nullptr; int ch0 = 0; float* ssum = nullptr; float* ssq = nullptr;
    if (yb == 0)      { in = xT; W = Wb;             bias = bq;
                        ssum = stat; ssq = stat + 64; ch0 = 0; }
    else if (yb == 1) { in = cT; W = Wb + K_ * CIN_; bias = bk;
                        outp = k_buf + (size_t)b * K_ * T_; }
    else { int m0 = (yb - 2) * 64; in = cT;
           W = Wb + 2 * K_ * CIN_ + (size_t)m0 * CIN_; bias = bv + m0;
           outp = v_raw + ((size_t)b * V_ + m0) * T_;
           ssum = stat + 128; ssq = stat + 384; ch0 = m0; }

    const int lane = tid & 63, w = tid >> 6;
    const int col = lane & 15, quad = lane >> 4;
    const int wm = tid >> 2, wp = tid & 3;
    const int xt = tid >> 1, xh = tid & 1;

    f32x4 acc[8];
    #pragma unroll
    for (int j = 0; j < 8; j++) acc[j] = (f32x4){0.f, 0.f, 0.f, 0.f};

    for (int c0 = 0; c0 < CIN_; c0 += 64) {
        {
            const unsigned short* ws = W + (size_t)wm * CIN_ + c0 + wp * 16;
            *(bf16x8*)&Wt[wm][wp * 16]     = *(const bf16x8*)(ws);
            *(bf16x8*)&Wt[wm][wp * 16 + 8] = *(const bf16x8*)(ws + 8);
            const unsigned short* xs = in + ((size_t)b * T_ + t0 + xt) * CIN_ + c0 + xh * 32;
            #pragma unroll
            for (int u = 0; u < 4; u++)
                *(bf16x8*)&Xt[xt][xh * 32 + 8 * u] = *(const bf16x8*)(xs + 8 * u);
        }
        __syncthreads();
        #pragma unroll
        for (int ks = 0; ks < 2; ks++) {
            const int kc = ks * 32 + quad * 8;
            bf16x8 af = *(bf16x8*)&Wt[w * 16 + col][kc];
            #pragma unroll
            for (int j = 0; j < 8; j++) {
                bf16x8 bfr = *(bf16x8*)&Xt[j * 16 + col][kc];
                acc[j] = __builtin_amdgcn_mfma_f32_16x16x32_bf16(af, bfr, acc[j], 0, 0, 0);
            }
        }
        __syncthreads();
    }

    float bias_v[4], s[4], sq[4];
    #pragma unroll
    for (int r = 0; r < 4; r++) {
        bias_v[r] = bias[w * 16 + quad * 4 + r];
        s[r] = 0.f; sq[r] = 0.f;
    }
    #pragma unroll
    for (int j = 0; j < 8; j++) {
        float o[4];
        #pragma unroll
        for (int r = 0; r < 4; r++) {
            o[r] = acc[j][r] + bias_v[r];
            s[r] += o[r]; sq[r] += o[r] * o[r];
        }
        if (yb == 0) {
            ushort4 h;
            h.x = f2bf(o[0]); h.y = f2bf(o[1]); h.z = f2bf(o[2]); h.w = f2bf(o[3]);
            *(ushort4*)(qT + ((size_t)b * T_ + t0 + j * 16 + col) * K_ + w * 16 + quad * 4) = h;
        } else {
            #pragma unroll
            for (int r = 0; r < 4; r++)
                outp[(size_t)(w * 16 + quad * 4 + r) * T_ + t0 + j * 16 + col] = o[r];
        }
    }
    if (ssum) {   // shuffle-reduce over the 16 cols of this quad group
        #pragma unroll
        for (int r = 0; r < 4; r++) {
            float sv = s[r], qv = sq[r];
            #pragma unroll
            for (int off = 1; off < 16; off <<= 1) {
                sv += __shfl_xor(sv, off, 64);
                qv += __shfl_xor(qv, off, 64);
            }
            if (col == 0) {
                int ch = ch0 + w * 16 + quad * 4 + r;
                atomicAdd(&ssum[ch], sv);
                atomicAdd(&ssq[ch], qv);
            }
        }
    }
}

// ---------------------------------------------------------------------------
// finalize: stats -> qprm/vprm scale+shift.  One block, 384 threads.
// ---------------------------------------------------------------------------
__global__ __launch_bounds__(384) void finalize_kernel(
    const float* __restrict__ stat,
    const float* __restrict__ gq, const float* __restrict__ betaq,
    const float* __restrict__ gv, const float* __restrict__ betav,
    float* __restrict__ qprm, float* __restrict__ vprm)
{
    const int i = threadIdx.x;
    const float inv_n = 1.f / (B_ * T_);
    if (i < K_) {
        float mean = stat[i] * inv_n;
        float var  = stat[64 + i] * inv_n - mean * mean;
        float sc = gq[i] * rsqrtf(var + EPS_);
        qprm[i] = sc; qprm[K_ + i] = betaq[i] - mean * sc;
    } else if (i < K_ + V_) {
        int c = i - K_;
        float mean = stat[128 + c] * inv_n;
        float var  = stat[384 + c] * inv_n - mean * mean;
        float sc = gv[c] * rsqrtf(var + EPS_);
        vprm[c] = sc; vprm[V_ + c] = betav[c] - mean * sc;
    }
}

// ---------------------------------------------------------------------------
// Softmax over T (unchanged)
// ---------------------------------------------------------------------------
__global__ __launch_bounds__(256) void softmax_kernel(float* __restrict__ k_buf)
{
    __shared__ float red[256];
    const int tid = threadIdx.x;
    float4* row = (float4*)(k_buf + (size_t)blockIdx.x * T_);
    float4 v = row[tid];
    float mx = fmaxf(fmaxf(v.x, v.y), fmaxf(v.z, v.w));
    red[tid] = mx; __syncthreads();
    for (int st = 128; st > 0; st >>= 1) {
        if (tid < st) red[tid] = fmaxf(red[tid], red[tid + st]);
        __syncthreads();
    }
    mx = red[0]; __syncthreads();
    float4 e;
    e.x = __expf(v.x - mx); e.y = __expf(v.y - mx);
    e.z = __expf(v.z - mx); e.w = __expf(v.w - mx);
    red[tid] = e.x + e.y + e.z + e.w; __syncthreads();
    for (int st = 128; st > 0; st >>= 1) {
        if (tid < st) red[tid] += red[tid + st];
        __syncthreads();
    }
    float inv = 1.f / red[0];
    e.x *= inv; e.y *= inv; e.z *= inv; e.w *= inv;
    row[tid] = e;
}

// ---------------------------------------------------------------------------
// lambda2 (unchanged): cl[b,k,v] += sum_t nk*v_raw  (t-split atomics)
// ---------------------------------------------------------------------------
__global__ __launch_bounds__(256) void lambda_kernel2(
    const float* __restrict__ k_buf, const float* __restrict__ v_raw,
    float* __restrict__ cl)
{
    __shared__ __align__(16) float nks[K_][68];
    __shared__ __align__(16) float vls[64][68];
    const int tid = threadIdx.x;
    const int b = blockIdx.z, v0 = blockIdx.y * 64, t0 = blockIdx.x * 64;
    {
        const int r = tid >> 2, q = tid & 3;
        const float* nrow = k_buf + ((size_t)b * K_ + r) * T_ + t0;
        const float* vrow = v_raw + ((size_t)b * V_ + v0 + r) * T_ + t0;
        #pragma unroll
        for (int i = 0; i < 4; i++) {
            int c4 = q + 4 * i;
            float4 g = *(const float4*)(nrow + 4 * c4);
            *(float4*)&nks[r][4 * c4] = g;
            float4 h = *(const float4*)(vrow + 4 * c4);
            vls[4 * c4 + 0][r] = h.x; vls[4 * c4 + 1][r] = h.y;
            vls[4 * c4 + 2][r] = h.z; vls[4 * c4 + 3][r] = h.w;
        }
    }
    __syncthreads();
    const int tv = tid & 15, tk = tid >> 4;
    float4 acc[4];
    #pragma unroll
    for (int i = 0; i < 4; i++) acc[i] = make_float4(0.f, 0.f, 0.f, 0.f);
    for (int tt = 0; tt < 16; tt++) {
        float4 w0 = *(float4*)&vls[4 * tt + 0][4 * tv];
        float4 w1 = *(float4*)&vls[4 * tt + 1][4 * tv];
        float4 w2 = *(float4*)&vls[4 * tt + 2][4 * tv];
        float4 w3 = *(float4*)&vls[4 * tt + 3][4 * tv];
        #pragma unroll
        for (int i = 0; i < 4; i++) {
            float4 n = *(float4*)&nks[4 * tk + i][4 * tt];
            acc[i] += w0 * n.x + w1 * n.y + w2 * n.z + w3 * n.w;
        }
    }
    #pragma unroll
    for (int i = 0; i < 4; i++) {
        float* ap = (float*)&acc[i];
        #pragma unroll
        for (int j = 0; j < 4; j++)
            atomicAdd(&cl[((size_t)b * K_ + 4 * tk + i) * V_ + v0 + 4 * tv + j], ap[j]);
    }
}

// ---------------------------------------------------------------------------
// prep_cl (unchanged)
// ---------------------------------------------------------------------------
__global__ __launch_bounds__(256) void prep_cl_kernel(
    const float* __restrict__ cl, const float* __restrict__ qprm,
    const float* __restrict__ vprm, unsigned short* __restrict__ clb2,
    float* __restrict__ hterm)
{
    __shared__ float red[4][64];
    const int tid = threadIdx.x;
    const int b = blockIdx.y, v0 = blockIdx.x * 64;
    const int vl = tid & 63, kq = tid >> 6;
    const float vsv = vprm[v0 + vl], vhv = vprm[V_ + v0 + vl];
    float h = 0.f;
    for (int kk = 0; kk < 16; kk++) {
        int k = kq * 16 + kk;
        float c = cl[((size_t)b * K_ + k) * V_ + v0 + vl];
        float clbv = c * vsv + vhv;
        h += qprm[K_ + k] * clbv;
        clb2[((size_t)b * V_ + v0 + vl) * K_ + k] = f2bf(clbv * qprm[k]);
    }
    red[kq][vl] = h;
    __syncthreads();
    if (tid < 64)
        hterm[(size_t)b * V_ + v0 + tid] =
            red[0][tid] + red[1][tid] + red[2][tid] + red[3][tid];
}

// ---------------------------------------------------------------------------
// qp3 (unchanged)
// ---------------------------------------------------------------------------
__global__ __launch_bounds__(256) void qp_kernel3(
    const unsigned short* __restrict__ qT, const float* __restrict__ pos_w,
    const float* __restrict__ pos_b, const float* __restrict__ qprm,
    float* __restrict__ qpT)
{
    __shared__ float pws[K_][24];
    __shared__ float consts[24];
    __shared__ float red[8][32][26];
    const int tid = threadIdx.x;
    for (int idx = tid; idx < K_ * 24; idx += 256) {
        int k = idx / 24, s = idx % 24;
        pws[k][s] = qprm[k] * (s < KS_ ? pos_w[k * KS_ + s] : pos_b[k]);
    }
    if (tid < 24) {
        float cs = 0.f;
        for (int k = 0; k < K_; k++)
            cs += qprm[K_ + k] * (tid < KS_ ? pos_w[k * KS_ + tid] : pos_b[k]);
        consts[tid] = cs;
    }
    __syncthreads();
    const int b = blockIdx.x >> 5, t0 = (blockIdx.x & 31) * 32;
    const int lt = tid & 31, ko = tid >> 5;
    float qf[8];
    {
        bf16x8 qv = *(const bf16x8*)(qT + ((size_t)b * T_ + t0 + lt) * K_ + ko * 8);
        #pragma unroll
        for (int i = 0; i < 8; i++) qf[i] = bf2f((unsigned short)qv[i]);
    }
    float accum[24];
    #pragma unroll
    for (int s = 0; s < 24; s++) accum[s] = 0.f;
    #pragma unroll
    for (int kk = 0; kk < 8; kk++) {
        float q = qf[kk];
        #pragma unroll
        for (int s = 0; s < 24; s++) accum[s] += q * pws[ko * 8 + kk][s];
    }
    #pragma unroll
    for (int s = 0; s < 24; s++) red[ko][lt][s] = accum[s];
    __syncthreads();
    for (int idx = tid; idx < 32 * 24; idx += 256) {
        int t = idx / 24, s = idx % 24;
        float v = consts[s];
        #pragma unroll
        for (int o = 0; o < 8; o++) v += red[o][t][s];
        qpT[((size_t)b * T_ + t0 + t) * 28 + s] = v;
    }
}

// ---------------------------------------------------------------------------
// out3 (unchanged)
// ---------------------------------------------------------------------------
__global__ __launch_bounds__(256) void out_kernel3(
    const unsigned short* __restrict__ qT, const unsigned short* __restrict__ clb2,
    const float* __restrict__ hterm, const float* __restrict__ qpT,
    const float* __restrict__ v_raw, const float* __restrict__ vprm,
    float* __restrict__ out)
{
    __shared__ unsigned short qTt[64][72];
    __shared__ unsigned short clv[64][72];
    __shared__ float vs2T[88][68];
    __shared__ float qpt[64][28];
    __shared__ float hvs[64];
    const int tid = threadIdx.x;
    const int b = blockIdx.z, v0 = blockIdx.y * 64, t0 = blockIdx.x * 64;

    {
        const int rl = tid >> 2, part = tid & 3;
        const unsigned short* qs = qT + ((size_t)b * T_ + t0 + rl) * K_ + part * 16;
        *(bf16x8*)&qTt[rl][part * 16]     = *(const bf16x8*)(qs);
        *(bf16x8*)&qTt[rl][part * 16 + 8] = *(const bf16x8*)(qs + 8);
        const unsigned short* cs = clb2 + ((size_t)b * V_ + v0 + rl) * K_ + part * 16;
        *(bf16x8*)&clv[rl][part * 16]     = *(const bf16x8*)(cs);
        *(bf16x8*)&clv[rl][part * 16 + 8] = *(const bf16x8*)(cs + 8);
    }
    {
        const float4* src = (const float4*)(qpT + ((size_t)b * T_ + t0) * 28);
        float4* dst = (float4*)&qpt[0][0];
        for (int idx = tid; idx < 64 * 28 / 4; idx += 256) dst[idx] = src[idx];
    }
    if (tid < 64) hvs[tid] = hterm[(size_t)b * V_ + v0 + tid];
    {
        const int vl = tid >> 2, qq = tid & 3;
        const float vsv = vprm[v0 + vl], vhv = vprm[V_ + v0 + vl];
        const float* vrow = v_raw + ((size_t)b * V_ + v0 + vl) * T_;
        #pragma unroll
        for (int i = 0; i < 22; i++) {
            int c = qq + 4 * i;
            if (c < 86) {
                int t = t0 + c - 11;
                vs2T[c][vl] = (t >= 0 && t < T_) ? vrow[t] * vsv + vhv : 0.f;
            }
        }
    }
    __syncthreads();

    const int lane = tid & 63, w = tid >> 6;
    const int col = lane & 15, quad = lane >> 4;

    f32x4 acc[4];
    #pragma unroll
    for (int tf = 0; tf < 4; tf++) acc[tf] = (f32x4){0.f, 0.f, 0.f, 0.f};

    #pragma unroll
    for (int ks = 0; ks < 2; ks++) {
        const int kc = ks * 32 + quad * 8;
        bf16x8 af = *(bf16x8*)&clv[w * 16 + col][kc];
        #pragma unroll
        for (int tf = 0; tf < 4; tf++) {
            bf16x8 bq = *(bf16x8*)&qTt[tf * 16 + col][kc];
            acc[tf] = __builtin_amdgcn_mfma_f32_16x16x32_bf16(af, bq, acc[tf], 0, 0, 0);
        }
    }

    const int vb = w * 16 + quad * 4;
    float4 hv4 = *(float4*)&hvs[vb];
    #pragma unroll
    for (int tf = 0; tf < 4; tf++) {
        const int lt = tf * 16 + col;
        float qv[24];
        #pragma unroll
        for (int u = 0; u < 6; u++)
            *(float4*)&qv[4 * u] = *(float4*)&qpt[lt][4 * u];
        float4 a; a.x = acc[tf][0]; a.y = acc[tf][1]; a.z = acc[tf][2]; a.w = acc[tf][3];
        #pragma unroll
        for (int s = 0; s < KS_; s++) {
            float4 wv = *(float4*)&vs2T[lt + s][vb];
            a.x += qv[s] * wv.x; a.y += qv[s] * wv.y;
            a.z += qv[s] * wv.z; a.w += qv[s] * wv.w;
        }
        float base = qv[23];
        a.x += base + hv4.x; a.y += base + hv4.y;
        a.z += base + hv4.z; a.w += base + hv4.w;
        float* ap = (float*)&a;
        #pragma unroll
        for (int r = 0; r < 4; r++)
            out[((size_t)b * V_ + v0 + vb + r) * T_ + t0 + lt] = ap[r];
    }
}

extern "C" void kernel_launch(void* const* d_in, const int* in_sizes, int n_in,
                              void* d_out, int out_size, void* d_ws, size_t ws_size,
                              hipStream_t stream)
{
    const float* x     = (const float*)d_in[0];
    const float* ctx   = (const float*)d_in[1];
    const float* Wq    = (const float*)d_in[2];
    const float* bq    = (const float*)d_in[3];
    const float* Wk    = (const float*)d_in[4];
    const float* bk    = (const float*)d_in[5];
    const float* Wv    = (const float*)d_in[6];
    const float* bv    = (const float*)d_in[7];
    const float* gq    = (const float*)d_in[8];
    const float* betaq = (const float*)d_in[9];
    const float* gv    = (const float*)d_in[10];
    const float* betav = (const float*)d_in[11];
    const float* pos_w = (const float*)d_in[12];
    const float* pos_b = (const float*)d_in[13];
    float* out = (float*)d_out;

    float* ws    = (float*)d_ws;
    float* k_buf = ws;                                   // B*K*T   = 524288
    float* v_raw = k_buf + (size_t)B_ * K_ * T_;         // B*V*T   = 2097152
    float* cl    = v_raw + (size_t)B_ * V_ * T_;         // B*K*V   = 131072
    float* stat  = cl + (size_t)B_ * K_ * V_;            // 640
    float* qpT   = stat + 640;                           // B*T*28  = 229376
    float* hterm = qpT + (size_t)B_ * T_ * 28;           // 2048
    float* qprm  = hterm + (size_t)B_ * V_;              // 128
    float* vprm  = qprm + 2 * K_;                        // 512
    unsigned short* xT   = (unsigned short*)(vprm + 2 * V_);   // B*T*CIN
    unsigned short* cT   = xT + (size_t)B_ * T_ * CIN_;        // B*T*CIN
    unsigned short* Wb   = cT + (size_t)B_ * T_ * CIN_;        // (2K+V)*CIN
    unsigned short* qT   = Wb + (size_t)(2 * K_ + V_) * CIN_;  // B*T*K
    unsigned short* clb2 = qT + (size_t)B_ * T_ * K_;          // B*V*K

    const int zero_n4 = (B_ * K_ * V_ + 640) / 4;   // cl + stats
    zero_kernel<<<dim3((zero_n4 + 255) / 256), 256, 0, stream>>>((float4*)cl, zero_n4);
    cvtT_kernel<<<dim3(T_ / 64, CIN_ / 64, 2 * B_), 256, 0, stream>>>(x, ctx, xT, cT);
    prew_kernel<<<dim3((2 * K_ + V_) * CIN_ / 1024), 256, 0, stream>>>(Wq, Wk, Wv, Wb);
    proj_mfma3<<<dim3(T_ / 128, 6, B_), 256, 0, stream>>>(
        xT, cT, Wb, bq, bk, bv, k_buf, v_raw, qT, stat);
    finalize_kernel<<<dim3(1), 384, 0, stream>>>(stat, gq, betaq, gv, betav, qprm, vprm);
    softmax_kernel<<<dim3(B_ * K_), 256, 0, stream>>>(k_buf);
    lambda_kernel2<<<dim3(T_ / 64, V_ / 64, B_), 256, 0, stream>>>(k_buf, v_raw, cl);
    prep_cl_kernel<<<dim3(V_ / 64, B_), 256, 0, stream>>>(cl, qprm, vprm, clb2, hterm);
    qp_kernel3<<<dim3(B_ * T_ / 32), 256, 0, stream>>>(qT, pos_w, pos_b, qprm, qpT);
    out_kernel3<<<dim3(T_ / 64, V_ / 64, B_), 256, 0, stream>>>(
        qT, clb2, hterm, qpT, v_raw, vprm, out);
}

// Round 7
// 161.421 us; speedup vs baseline: 1.6982x; 1.1318x over previous
//
#include <hip/hip_runtime.h>
#include <math.h>

#define B_ 8
#define CIN_ 512
#define K_ 64
#define V_ 256
#define T_ 1024
#define KS_ 23
#define EPS_ 1e-5f
#define NTC_ 16   // lambda t-chunks (partials)

typedef __attribute__((ext_vector_type(8))) short bf16x8;
typedef __attribute__((ext_vector_type(4))) float f32x4;

__device__ __forceinline__ unsigned short f2bf(float f) {
    union { float f; unsigned u; } x; x.f = f;
    unsigned r = x.u + 0x7fffu + ((x.u >> 16) & 1u);   // RNE
    return (unsigned short)(r >> 16);
}
__device__ __forceinline__ float bf2f(unsigned short h) {
    union { unsigned u; float f; } x; x.u = ((unsigned)h) << 16;
    return x.f;
}

// ---------------------------------------------------------------------------
// cvtT: src[b][c][t] f32 -> dst[b][t][c] bf16.  64x64 tiles via LDS.
// ---------------------------------------------------------------------------
__global__ __launch_bounds__(256) void cvtT_kernel(
    const float* __restrict__ x, const float* __restrict__ ctx,
    unsigned short* __restrict__ xT, unsigned short* __restrict__ cT)
{
    __shared__ unsigned short sh[64][72];
    const int tid = threadIdx.x;
    const int t0 = blockIdx.x * 64, c0 = blockIdx.y * 64;
    const int b = blockIdx.z & 7, which = blockIdx.z >> 3;
    const float* src = which ? ctx : x;
    unsigned short* dst = which ? cT : xT;

    const int cl = tid >> 2, qq = tid & 3;
    const float* row = src + ((size_t)b * CIN_ + c0 + cl) * T_ + t0 + qq * 16;
    #pragma unroll
    for (int u = 0; u < 4; u++) {
        float4 f = *(const float4*)(row + 4 * u);
        sh[qq * 16 + 4 * u + 0][cl] = f2bf(f.x);
        sh[qq * 16 + 4 * u + 1][cl] = f2bf(f.y);
        sh[qq * 16 + 4 * u + 2][cl] = f2bf(f.z);
        sh[qq * 16 + 4 * u + 3][cl] = f2bf(f.w);
    }
    __syncthreads();
    const int tl = tid >> 2;
    unsigned short* orow = dst + ((size_t)b * T_ + t0 + tl) * CIN_ + c0 + qq * 16;
    *(bf16x8*)(orow)     = *(bf16x8*)&sh[tl][qq * 16];
    *(bf16x8*)(orow + 8) = *(bf16x8*)&sh[tl][qq * 16 + 8];
}

// ---------------------------------------------------------------------------
// prew: Wq|Wk|Wv fp32 -> bf16 concatenated.  Block 0 also zeroes stat[640].
// ---------------------------------------------------------------------------
__global__ __launch_bounds__(256) void prew_kernel(
    const float* __restrict__ Wq, const float* __restrict__ Wk,
    const float* __restrict__ Wv, unsigned short* __restrict__ Wb,
    float* __restrict__ stat)
{
    if (blockIdx.x == 0 && threadIdx.x < 160)
        ((float4*)stat)[threadIdx.x] = make_float4(0.f, 0.f, 0.f, 0.f);
    const int i4 = blockIdx.x * 256 + threadIdx.x;
    const int n1 = K_ * CIN_ / 4, n2 = 2 * K_ * CIN_ / 4;
    const float* src; int off;
    if (i4 < n1)      { src = Wq; off = i4; }
    else if (i4 < n2) { src = Wk; off = i4 - n1; }
    else              { src = Wv; off = i4 - n2; }
    float4 f = ((const float4*)src)[off];
    ushort4 h;
    h.x = f2bf(f.x); h.y = f2bf(f.y); h.z = f2bf(f.z); h.w = f2bf(f.w);
    *(ushort4*)(Wb + (size_t)i4 * 4) = h;
}

// ---------------------------------------------------------------------------
// proj_mfma3: bf16 MFMA projection + fused BN channel stats (atomics).
// stat: [0:64) qsum, [64:128) qsq, [128:384) vsum, [384:640) vsq
// ---------------------------------------------------------------------------
__global__ __launch_bounds__(256) void proj_mfma3(
    const unsigned short* __restrict__ xT, const unsigned short* __restrict__ cT,
    const unsigned short* __restrict__ Wb,
    const float* __restrict__ bq, const float* __restrict__ bk,
    const float* __restrict__ bv,
    float* __restrict__ k_buf, float* __restrict__ v_raw,
    unsigned short* __restrict__ qT, float* __restrict__ stat)
{
    __shared__ unsigned short Wt[64][72];
    __shared__ unsigned short Xt[128][72];
    const int tid = threadIdx.x;
    const int b = blockIdx.z, t0 = blockIdx.x * 128, yb = blockIdx.y;

    const unsigned short* in; const unsigned short* W; const float* bias;
    float* outp = nullptr; int ch0 = 0; float* ssum = nullptr; float* ssq = nullptr;
    if (yb == 0)      { in = xT; W = Wb;             bias = bq;
                        ssum = stat; ssq = stat + 64; ch0 = 0; }
    else if (yb == 1) { in = cT; W = Wb + K_ * CIN_; bias = bk;
                        outp = k_buf + (size_t)b * K_ * T_; }
    else { int m0 = (yb - 2) * 64; in = cT;
           W = Wb + 2 * K_ * CIN_ + (size_t)m0 * CIN_; bias = bv + m0;
           outp = v_raw + ((size_t)b * V_ + m0) * T_;
           ssum = stat + 128; ssq = stat + 384; ch0 = m0; }

    const int lane = tid & 63, w = tid >> 6;
    const int col = lane & 15, quad = lane >> 4;
    const int wm = tid >> 2, wp = tid & 3;
    const int xt = tid >> 1, xh = tid & 1;

    f32x4 acc[8];
    #pragma unroll
    for (int j = 0; j < 8; j++) acc[j] = (f32x4){0.f, 0.f, 0.f, 0.f};

    for (int c0 = 0; c0 < CIN_; c0 += 64) {
        {
            const unsigned short* ws = W + (size_t)wm * CIN_ + c0 + wp * 16;
            *(bf16x8*)&Wt[wm][wp * 16]     = *(const bf16x8*)(ws);
            *(bf16x8*)&Wt[wm][wp * 16 + 8] = *(const bf16x8*)(ws + 8);
            const unsigned short* xs = in + ((size_t)b * T_ + t0 + xt) * CIN_ + c0 + xh * 32;
            #pragma unroll
            for (int u = 0; u < 4; u++)
                *(bf16x8*)&Xt[xt][xh * 32 + 8 * u] = *(const bf16x8*)(xs + 8 * u);
        }
        __syncthreads();
        #pragma unroll
        for (int ks = 0; ks < 2; ks++) {
            const int kc = ks * 32 + quad * 8;
            bf16x8 af = *(bf16x8*)&Wt[w * 16 + col][kc];
            #pragma unroll
            for (int j = 0; j < 8; j++) {
                bf16x8 bfr = *(bf16x8*)&Xt[j * 16 + col][kc];
                acc[j] = __builtin_amdgcn_mfma_f32_16x16x32_bf16(af, bfr, acc[j], 0, 0, 0);
            }
        }
        __syncthreads();
    }

    float bias_v[4], s[4], sq[4];
    #pragma unroll
    for (int r = 0; r < 4; r++) {
        bias_v[r] = bias[w * 16 + quad * 4 + r];
        s[r] = 0.f; sq[r] = 0.f;
    }
    #pragma unroll
    for (int j = 0; j < 8; j++) {
        float o[4];
        #pragma unroll
        for (int r = 0; r < 4; r++) {
            o[r] = acc[j][r] + bias_v[r];
            s[r] += o[r]; sq[r] += o[r] * o[r];
        }
        if (yb == 0) {
            ushort4 h;
            h.x = f2bf(o[0]); h.y = f2bf(o[1]); h.z = f2bf(o[2]); h.w = f2bf(o[3]);
            *(ushort4*)(qT + ((size_t)b * T_ + t0 + j * 16 + col) * K_ + w * 16 + quad * 4) = h;
        } else {
            #pragma unroll
            for (int r = 0; r < 4; r++)
                outp[(size_t)(w * 16 + quad * 4 + r) * T_ + t0 + j * 16 + col] = o[r];
        }
    }
    if (ssum) {
        #pragma unroll
        for (int r = 0; r < 4; r++) {
            float sv = s[r], qv = sq[r];
            #pragma unroll
            for (int off = 1; off < 16; off <<= 1) {
                sv += __shfl_xor(sv, off, 64);
                qv += __shfl_xor(qv, off, 64);
            }
            if (col == 0) {
                int ch = ch0 + w * 16 + quad * 4 + r;
                atomicAdd(&ssum[ch], sv);
                atomicAdd(&ssq[ch], qv);
            }
        }
    }
}

// ---------------------------------------------------------------------------
// Softmax over T (unchanged)
// ---------------------------------------------------------------------------
__global__ __launch_bounds__(256) void softmax_kernel(float* __restrict__ k_buf)
{
    __shared__ float red[256];
    const int tid = threadIdx.x;
    float4* row = (float4*)(k_buf + (size_t)blockIdx.x * T_);
    float4 v = row[tid];
    float mx = fmaxf(fmaxf(v.x, v.y), fmaxf(v.z, v.w));
    red[tid] = mx; __syncthreads();
    for (int st = 128; st > 0; st >>= 1) {
        if (tid < st) red[tid] = fmaxf(red[tid], red[tid + st]);
        __syncthreads();
    }
    mx = red[0]; __syncthreads();
    float4 e;
    e.x = __expf(v.x - mx); e.y = __expf(v.y - mx);
    e.z = __expf(v.z - mx); e.w = __expf(v.w - mx);
    red[tid] = e.x + e.y + e.z + e.w; __syncthreads();
    for (int st = 128; st > 0; st >>= 1) {
        if (tid < st) red[tid] += red[tid + st];
        __syncthreads();
    }
    float inv = 1.f / red[0];
    e.x *= inv; e.y *= inv; e.z *= inv; e.w *= inv;
    row[tid] = e;
}

// ---------------------------------------------------------------------------
// lambda3: clp[b,tc,k,v] = sum_{t in chunk} nk[b,k,t]*v_raw[b,v,t]
// Partial-sum version of lambda2: plain stores, no zero-init, no atomics.
// ---------------------------------------------------------------------------
__global__ __launch_bounds__(256) void lambda_kernel3(
    const float* __restrict__ k_buf, const float* __restrict__ v_raw,
    float* __restrict__ clp)
{
    __shared__ __align__(16) float nks[K_][68];
    __shared__ __align__(16) float vls[64][68];
    const int tid = threadIdx.x;
    const int b = blockIdx.z, v0 = blockIdx.y * 64, tc = blockIdx.x, t0 = tc * 64;
    {
        const int r = tid >> 2, q = tid & 3;
        const float* nrow = k_buf + ((size_t)b * K_ + r) * T_ + t0;
        const float* vrow = v_raw + ((size_t)b * V_ + v0 + r) * T_ + t0;
        #pragma unroll
        for (int i = 0; i < 4; i++) {
            int c4 = q + 4 * i;
            float4 g = *(const float4*)(nrow + 4 * c4);
            *(float4*)&nks[r][4 * c4] = g;
            float4 h = *(const float4*)(vrow + 4 * c4);
            vls[4 * c4 + 0][r] = h.x; vls[4 * c4 + 1][r] = h.y;
            vls[4 * c4 + 2][r] = h.z; vls[4 * c4 + 3][r] = h.w;
        }
    }
    __syncthreads();
    const int tv = tid & 15, tk = tid >> 4;
    float4 acc[4];
    #pragma unroll
    for (int i = 0; i < 4; i++) acc[i] = make_float4(0.f, 0.f, 0.f, 0.f);
    for (int tt = 0; tt < 16; tt++) {
        float4 w0 = *(float4*)&vls[4 * tt + 0][4 * tv];
        float4 w1 = *(float4*)&vls[4 * tt + 1][4 * tv];
        float4 w2 = *(float4*)&vls[4 * tt + 2][4 * tv];
        float4 w3 = *(float4*)&vls[4 * tt + 3][4 * tv];
        #pragma unroll
        for (int i = 0; i < 4; i++) {
            float4 n = *(float4*)&nks[4 * tk + i][4 * tt];
            acc[i] += w0 * n.x + w1 * n.y + w2 * n.z + w3 * n.w;
        }
    }
    #pragma unroll
    for (int i = 0; i < 4; i++)
        *(float4*)&clp[(((size_t)b * NTC_ + tc) * K_ + 4 * tk + i) * V_ + v0 + 4 * tv] = acc[i];
}

// ---------------------------------------------------------------------------
// prep_cl2: sum clp partials; BN params computed inline from stat.
// clb2[b][v][k] = bf16((cl*vs+vh)*qs[k]);  hterm[b][v] = sum_k qh[k]*(cl*vs+vh)
// ---------------------------------------------------------------------------
__global__ __launch_bounds__(256) void prep_cl_kernel2(
    const float* __restrict__ clp, const float* __restrict__ stat,
    const float* __restrict__ gq, const float* __restrict__ betaq,
    const float* __restrict__ gv, const float* __restrict__ betav,
    unsigned short* __restrict__ clb2, float* __restrict__ hterm)
{
    __shared__ float qsc[64], qsh[64], red[4][64];
    const int tid = threadIdx.x;
    const int b = blockIdx.y, v0 = blockIdx.x * 64;
    const float inv_n = 1.f / (B_ * T_);
    if (tid < 64) {
        float mean = stat[tid] * inv_n;
        float var  = stat[64 + tid] * inv_n - mean * mean;
        float sc = gq[tid] * rsqrtf(var + EPS_);
        qsc[tid] = sc; qsh[tid] = betaq[tid] - mean * sc;
    }
    const int vl = tid & 63, kq = tid >> 6;
    const int c = v0 + vl;
    float vmean = stat[128 + c] * inv_n;
    float vvar  = stat[384 + c] * inv_n - vmean * vmean;
    float vsv = gv[c] * rsqrtf(vvar + EPS_);
    float vhv = betav[c] - vmean * vsv;
    __syncthreads();
    float h = 0.f;
    for (int kk = 0; kk < 16; kk++) {
        int k = kq * 16 + kk;
        float a = 0.f;
        #pragma unroll
        for (int tc = 0; tc < NTC_; tc++)
            a += clp[(((size_t)b * NTC_ + tc) * K_ + k) * V_ + c];
        float clbv = a * vsv + vhv;
        h += qsh[k] * clbv;
        clb2[((size_t)b * V_ + c) * K_ + k] = f2bf(clbv * qsc[k]);
    }
    red[kq][vl] = h;
    __syncthreads();
    if (tid < 64)
        hterm[(size_t)b * V_ + v0 + tid] =
            red[0][tid] + red[1][tid] + red[2][tid] + red[3][tid];
}

// ---------------------------------------------------------------------------
// out4: fused qp + content-MFMA + conv epilogue.
// out[b,v,t] = MFMA(clb2,qT) + hterm[v] + qp[t][23]
//            + sum_s qp[t][s]*vbn[v][t+s-11]
// qp computed in-block from staged qTt (kills qp kernel + qpT round-trip);
// BN params computed inline from stat.
// ---------------------------------------------------------------------------
__global__ __launch_bounds__(256) void out_kernel4(
    const unsigned short* __restrict__ qT, const unsigned short* __restrict__ clb2,
    const float* __restrict__ hterm, const float* __restrict__ v_raw,
    const float* __restrict__ stat,
    const float* __restrict__ gq, const float* __restrict__ betaq,
    const float* __restrict__ gv, const float* __restrict__ betav,
    const float* __restrict__ pos_w, const float* __restrict__ pos_b,
    float* __restrict__ out)
{
    __shared__ unsigned short qTt[64][72];   // [t][k]
    __shared__ unsigned short clv[64][72];   // [v][k]
    __shared__ float vs2T[88][68];           // [c][v]
    __shared__ float qpt[64][24];            // [t][s], s=23 is qb
    __shared__ float pws[64][24];            // qsc[k]*pos
    __shared__ float qsc[64], qsh[64];
    __shared__ float consts[24];
    __shared__ float hvs[64];
    const int tid = threadIdx.x;
    const int b = blockIdx.z, v0 = blockIdx.y * 64, t0 = blockIdx.x * 64;
    const float inv_n = 1.f / (B_ * T_);

    // ---- phase A: stage tiles + BN params ----
    if (tid < 64) {
        float mean = stat[tid] * inv_n;
        float var  = stat[64 + tid] * inv_n - mean * mean;
        float sc = gq[tid] * rsqrtf(var + EPS_);
        qsc[tid] = sc; qsh[tid] = betaq[tid] - mean * sc;
        hvs[tid] = hterm[(size_t)b * V_ + v0 + tid];
    }
    {
        const int rl = tid >> 2, part = tid & 3;
        const unsigned short* qs = qT + ((size_t)b * T_ + t0 + rl) * K_ + part * 16;
        *(bf16x8*)&qTt[rl][part * 16]     = *(const bf16x8*)(qs);
        *(bf16x8*)&qTt[rl][part * 16 + 8] = *(const bf16x8*)(qs + 8);
        const unsigned short* cs = clb2 + ((size_t)b * V_ + v0 + rl) * K_ + part * 16;
        *(bf16x8*)&clv[rl][part * 16]     = *(const bf16x8*)(cs);
        *(bf16x8*)&clv[rl][part * 16 + 8] = *(const bf16x8*)(cs + 8);
    }
    {
        const int vl = tid >> 2, qq = tid & 3;
        const int c = v0 + vl;
        float vmean = stat[128 + c] * inv_n;
        float vvar  = stat[384 + c] * inv_n - vmean * vmean;
        float vsv = gv[c] * rsqrtf(vvar + EPS_);
        float vhv = betav[c] - vmean * vsv;
        const float* vrow = v_raw + ((size_t)b * V_ + c) * T_;
        #pragma unroll
        for (int i = 0; i < 22; i++) {
            int cc = qq + 4 * i;
            if (cc < 86) {
                int t = t0 + cc - 11;
                vs2T[cc][vl] = (t >= 0 && t < T_) ? vrow[t] * vsv + vhv : 0.f;
            }
        }
    }
    __syncthreads();

    // ---- phase B: pws + consts ----
    for (int idx = tid; idx < K_ * 24; idx += 256) {
        int k = idx / 24, s = idx % 24;
        pws[k][s] = qsc[k] * (s < KS_ ? pos_w[k * KS_ + s] : pos_b[k]);
    }
    if (tid < 24) {
        float cs = 0.f;
        for (int k = 0; k < K_; k++)
            cs += qsh[k] * (tid < KS_ ? pos_w[k * KS_ + tid] : pos_b[k]);
        consts[tid] = cs;
    }
    __syncthreads();

    // ---- phase C: qpt[t][s] = consts[s] + sum_k qTt[t][k]*pws[k][s] ----
    {
        const int t = tid >> 2, sg = tid & 3, s0 = sg * 6;
        float a[6];
        #pragma unroll
        for (int u = 0; u < 6; u++) a[u] = consts[s0 + u];
        #pragma unroll
        for (int kb = 0; kb < 8; kb++) {
            bf16x8 qv = *(bf16x8*)&qTt[t][kb * 8];
            #pragma unroll
            for (int j = 0; j < 8; j++) {
                float q = bf2f((unsigned short)qv[j]);
                #pragma unroll
                for (int u = 0; u < 6; u++) a[u] += q * pws[kb * 8 + j][s0 + u];
            }
        }
        #pragma unroll
        for (int u = 0; u < 6; u++) qpt[t][s0 + u] = a[u];
    }
    __syncthreads();

    // ---- phase D: MFMA + conv epilogue ----
    const int lane = tid & 63, w = tid >> 6;
    const int col = lane & 15, quad = lane >> 4;

    f32x4 acc[4];
    #pragma unroll
    for (int tf = 0; tf < 4; tf++) acc[tf] = (f32x4){0.f, 0.f, 0.f, 0.f};

    #pragma unroll
    for (int ks = 0; ks < 2; ks++) {
        const int kc = ks * 32 + quad * 8;
        bf16x8 af = *(bf16x8*)&clv[w * 16 + col][kc];
        #pragma unroll
        for (int tf = 0; tf < 4; tf++) {
            bf16x8 bq = *(bf16x8*)&qTt[tf * 16 + col][kc];
            acc[tf] = __builtin_amdgcn_mfma_f32_16x16x32_bf16(af, bq, acc[tf], 0, 0, 0);
        }
    }

    const int vb = w * 16 + quad * 4;
    float4 hv4 = *(float4*)&hvs[vb];
    #pragma unroll
    for (int tf = 0; tf < 4; tf++) {
        const int lt = tf * 16 + col;
        float qv[24];
        #pragma unroll
        for (int u = 0; u < 6; u++)
            *(float4*)&qv[4 * u] = *(float4*)&qpt[lt][4 * u];
        float4 a; a.x = acc[tf][0]; a.y = acc[tf][1]; a.z = acc[tf][2]; a.w = acc[tf][3];
        #pragma unroll
        for (int s = 0; s < KS_; s++) {
            float4 wv = *(float4*)&vs2T[lt + s][vb];
            a.x += qv[s] * wv.x; a.y += qv[s] * wv.y;
            a.z += qv[s] * wv.z; a.w += qv[s] * wv.w;
        }
        float base = qv[23];
        a.x += base + hv4.x; a.y += base + hv4.y;
        a.z += base + hv4.z; a.w += base + hv4.w;
        float* ap = (float*)&a;
        #pragma unroll
        for (int r = 0; r < 4; r++)
            out[((size_t)b * V_ + v0 + vb + r) * T_ + t0 + lt] = ap[r];
    }
}

extern "C" void kernel_launch(void* const* d_in, const int* in_sizes, int n_in,
                              void* d_out, int out_size, void* d_ws, size_t ws_size,
                              hipStream_t stream)
{
    const float* x     = (const float*)d_in[0];
    const float* ctx   = (const float*)d_in[1];
    const float* Wq    = (const float*)d_in[2];
    const float* bq    = (const float*)d_in[3];
    const float* Wk    = (const float*)d_in[4];
    const float* bk    = (const float*)d_in[5];
    const float* Wv    = (const float*)d_in[6];
    const float* bv    = (const float*)d_in[7];
    const float* gq    = (const float*)d_in[8];
    const float* betaq = (const float*)d_in[9];
    const float* gv    = (const float*)d_in[10];
    const float* betav = (const float*)d_in[11];
    const float* pos_w = (const float*)d_in[12];
    const float* pos_b = (const float*)d_in[13];
    float* out = (float*)d_out;

    float* ws    = (float*)d_ws;
    float* k_buf = ws;                                   // B*K*T      = 524288
    float* v_raw = k_buf + (size_t)B_ * K_ * T_;         // B*V*T      = 2097152
    float* clp   = v_raw + (size_t)B_ * V_ * T_;         // B*NTC*K*V  = 2097152
    float* stat  = clp + (size_t)B_ * NTC_ * K_ * V_;    // 640
    float* hterm = stat + 640;                           // B*V = 2048
    unsigned short* xT   = (unsigned short*)(hterm + (size_t)B_ * V_);
    unsigned short* cT   = xT + (size_t)B_ * T_ * CIN_;
    unsigned short* Wb   = cT + (size_t)B_ * T_ * CIN_;
    unsigned short* qT   = Wb + (size_t)(2 * K_ + V_) * CIN_;
    unsigned short* clb2 = qT + (size_t)B_ * T_ * K_;

    cvtT_kernel<<<dim3(T_ / 64, CIN_ / 64, 2 * B_), 256, 0, stream>>>(x, ctx, xT, cT);
    prew_kernel<<<dim3((2 * K_ + V_) * CIN_ / 1024), 256, 0, stream>>>(Wq, Wk, Wv, Wb, stat);
    proj_mfma3<<<dim3(T_ / 128, 6, B_), 256, 0, stream>>>(
        xT, cT, Wb, bq, bk, bv, k_buf, v_raw, qT, stat);
    softmax_kernel<<<dim3(B_ * K_), 256, 0, stream>>>(k_buf);
    lambda_kernel3<<<dim3(NTC_, V_ / 64, B_), 256, 0, stream>>>(k_buf, v_raw, clp);
    prep_cl_kernel2<<<dim3(V_ / 64, B_), 256, 0, stream>>>(
        clp, stat, gq, betaq, gv, betav, clb2, hterm);
    out_kernel4<<<dim3(T_ / 64, V_ / 64, B_), 256, 0, stream>>>(
        qT, clb2, hterm, v_raw, stat, gq, betaq, gv, betav, pos_w, pos_b, out);
}